// Round 5
// baseline (565.348 us; speedup 1.0000x reference)
//
#include <hip/hip_runtime.h>
#include <math.h>
#include <stdint.h>

#define S_LEN 8192
#define HID   1280
#define NH    16
#define HD    80
#define LCH   1024
#define NCH   8

typedef __attribute__((ext_vector_type(8))) short bf16x8;
typedef __attribute__((ext_vector_type(8))) unsigned short u16x8;
typedef __attribute__((ext_vector_type(4))) float f32x4;

__device__ __forceinline__ uint16_t f2bf(float f) {
    union { float f; uint32_t u; } v; v.f = f;
    uint32_t r = v.u + 0x7FFF + ((v.u >> 16) & 1);   // RNE
    return (uint16_t)(r >> 16);
}
__device__ __forceinline__ float bf2f(uint16_t h) {
    union { uint32_t u; float f; } v; v.u = ((uint32_t)h) << 16;
    return v.f;
}
__device__ __forceinline__ uint32_t pk2(float a, float b) {   // trunc-bf16 pair pack
    union { float f; uint32_t u; } x, y; x.f = a; y.f = b;
    return (x.u >> 16) | (y.u & 0xFFFF0000u);
}

__device__ __forceinline__ void glds16(const void* g, void* l) {
    __builtin_amdgcn_global_load_lds(
        (const __attribute__((address_space(1))) uint32_t*)g,
        (__attribute__((address_space(3))) uint32_t*)l,
        16, 0, 0);
}

#define MFMA16(a, b, c) __builtin_amdgcn_mfma_f32_16x16x32_bf16(a, b, c, 0, 0, 0)
#define SB()  __builtin_amdgcn_sched_barrier(0)
#define BAR() __builtin_amdgcn_s_barrier()

__device__ __forceinline__ void vmwait0() {
    asm volatile("s_waitcnt vmcnt(0)" ::: "memory");
}

// stage one [rows x 32] bf16 K-tile (nbytes = rows*64) into LDS, linear dest,
// global source pre-swizzled per lane so the ds_read-side XOR swizzle matches.
// chunk advance: 1024 B LDS <-> 16 rows * 2560 B global = off*40.
__device__ __forceinline__ void stage_tile(const char* gsrc, char* dst, int w,
                                           int kt, int nbytes)
{
    const char* sp = gsrc + (size_t)kt * 64;
    int off = w * 1024;
    glds16(sp + (size_t)off * 40, dst + off);
    off += 8192;
    if (off < nbytes) glds16(sp + (size_t)off * 40, dst + off);
}

// ---------------- prepass: split x fp32 -> hi/lo bf16 (same layout) ----------------
__global__ __launch_bounds__(256)
void xsplit_kernel(const float* __restrict__ x, uint16_t* __restrict__ xh,
                   uint16_t* __restrict__ xl)
{
    int idx = (blockIdx.x * 256 + threadIdx.x) * 4;
    float4 v = *(const float4*)(x + idx);
    ushort4 hi, lo;
    hi.x = f2bf(v.x); lo.x = f2bf(v.x - bf2f(hi.x));
    hi.y = f2bf(v.y); lo.y = f2bf(v.y - bf2f(hi.y));
    hi.z = f2bf(v.z); lo.z = f2bf(v.z - bf2f(hi.z));
    hi.w = f2bf(v.w); lo.w = f2bf(v.w - bf2f(hi.w));
    *(ushort4*)(xh + idx) = hi;
    *(ushort4*)(xl + idx) = lo;
}

// ---------------- prepass: W [1280][ND] fp32 -> W^T [ND][1280] hi/lo bf16 ----------------
template<int ND>
__global__ __launch_bounds__(256)
void wsplit_kernel(const float* __restrict__ W, uint16_t* __restrict__ Wth,
                   uint16_t* __restrict__ Wtl)
{
    __shared__ float t[32][33];
    const int tid = threadIdx.x;
    const int n0 = blockIdx.x * 32;
    const int k0 = blockIdx.y * 32;
    for (int i = tid; i < 1024; i += 256) {
        int r = i >> 5, c = i & 31;
        t[r][c] = W[(size_t)(k0 + r) * ND + n0 + c];
    }
    __syncthreads();
    for (int i = tid; i < 1024; i += 256) {
        int r = i >> 5, c = i & 31;          // r: n offset, c: k offset
        float f = t[c][r];
        uint16_t hi = f2bf(f);
        size_t o = (size_t)(n0 + r) * HID + k0 + c;
        Wth[o] = hi;
        Wtl[o] = f2bf(f - bf2f(hi));
    }
}

// ---------------- split-bf16 MFMA GEMM, 256-wide tile, SINGLE-barrier K-loop ----------
// Per K-tile: {vmcnt(0); s_barrier; issue 8 glds16 -> buffer t; read 24 frags
// from buffer s; 96 MFMA (hh, hl, lh)}. Correctness: staging targets t while all
// reads hit s; tile kt-1's reads of t were register-consumed before the barrier,
// so one barrier per K-tile suffices. vmcnt(0) drains only the 8 staging calls
// issued one full K-tile (~900+ cyc) earlier. XCD-aware bijective block swizzle
// (NWG%8==0) makes each XCD's chunk span 1-2 B-panels -> B L2-resident.
template<int ND, int BN, int NWN, int EPI>
__global__ __launch_bounds__(512, 2)
void gemm1b(const uint16_t* __restrict__ Ahp, const uint16_t* __restrict__ Alp,
            const uint16_t* __restrict__ Bth, const uint16_t* __restrict__ Btl,
            const float* __restrict__ bias, float* __restrict__ oF,
            uint16_t* __restrict__ oq, uint16_t* __restrict__ ok,
            uint16_t* __restrict__ ov)
{
    constexpr int NWM = 8 / NWN;
    constexpr int MI  = 256 / (NWM * 16);
    constexpr int NI  = BN / (NWN * 16);
    constexpr int ABYTES = 256 * 64;
    constexpr int BBYTES = BN * 64;
    constexpr int NT = HID / 32;             // 40 K-tiles
    constexpr int NBX = ND / BN;             // grid.x
    constexpr int NWG = NBX * 32;            // grid size (%8 == 0)
    constexpr int CPX = NWG / 8;
    static_assert(BN % (NWN * 16) == 0, "tile split");
    static_assert(NWG % 8 == 0, "xcd swizzle");

    __shared__ __align__(1024) uint16_t AsH[2][ABYTES / 2];
    __shared__ __align__(1024) uint16_t AsL[2][ABYTES / 2];
    __shared__ __align__(1024) uint16_t BsH[2][BBYTES / 2];
    __shared__ __align__(1024) uint16_t BsL[2][BBYTES / 2];

    const int tid  = threadIdx.x;
    const int w    = tid >> 6;
    const int lane = tid & 63;
    const int quad = lane >> 4;
    const int l16  = lane & 15;
    const int wm   = w / NWN;
    const int wn   = w % NWN;

    // XCD-aware bijective swizzle on the hardware linear id
    const int hwid = blockIdx.y * NBX + blockIdx.x;
    const int nid  = (hwid & 7) * CPX + (hwid >> 3);
    const int n0 = (nid >> 5) * BN;          // grid.y == 32
    const int m0 = (nid & 31) * 256;

    const size_t stg = (size_t)(lane >> 2) * (HID * 2)
                     + (size_t)(((lane & 3) ^ ((lane >> 3) & 3)) << 4);
    const char* gAh = (const char*)Ahp + (size_t)m0 * (HID * 2) + stg;
    const char* gAl = (const char*)Alp + (size_t)m0 * (HID * 2) + stg;
    const char* gBh = (const char*)Bth + (size_t)n0 * (HID * 2) + stg;
    const char* gBl = (const char*)Btl + (size_t)n0 * (HID * 2) + stg;

    const int swz  = (quad ^ ((l16 >> 1) & 3)) << 4;
    const int aoff = (wm * (MI * 16) + l16) * 64 + swz;
    const int boff = (wn * (NI * 16) + l16) * 64 + swz;

    f32x4 acc[MI][NI];
    #pragma unroll
    for (int mi = 0; mi < MI; ++mi)
        #pragma unroll
        for (int ni = 0; ni < NI; ++ni) acc[mi][ni] = (f32x4){0.f, 0.f, 0.f, 0.f};

    // prologue: stage kt=0 into buffers [0]
    stage_tile(gAh, (char*)AsH[0], w, 0, ABYTES);
    stage_tile(gBh, (char*)BsH[0], w, 0, BBYTES);
    stage_tile(gBl, (char*)BsL[0], w, 0, BBYTES);
    stage_tile(gAl, (char*)AsL[0], w, 0, ABYTES);

    for (int kt = 0; kt < NT; ++kt) {
        const int s = kt & 1, t = s ^ 1;

        SB(); vmwait0(); BAR(); SB();        // buffer s fully landed (all waves)

        if (kt + 1 < NT) {                   // issue next tile early (hides HBM latency)
            stage_tile(gAh, (char*)AsH[t], w, kt + 1, ABYTES);
            stage_tile(gBh, (char*)BsH[t], w, kt + 1, BBYTES);
            stage_tile(gBl, (char*)BsL[t], w, kt + 1, BBYTES);
            stage_tile(gAl, (char*)AsL[t], w, kt + 1, ABYTES);
        }

        bf16x8 ah[MI], bh[NI];
        #pragma unroll
        for (int mi = 0; mi < MI; ++mi)
            ah[mi] = *(const bf16x8*)((const char*)AsH[s] + aoff + mi * 1024);
        #pragma unroll
        for (int ni = 0; ni < NI; ++ni)
            bh[ni] = *(const bf16x8*)((const char*)BsH[s] + boff + ni * 1024);

        __builtin_amdgcn_s_setprio(1);
        #pragma unroll
        for (int mi = 0; mi < MI; ++mi)
            #pragma unroll
            for (int ni = 0; ni < NI; ++ni)
                acc[mi][ni] = MFMA16(ah[mi], bh[ni], acc[mi][ni]);

        bf16x8 bl[NI];
        #pragma unroll
        for (int ni = 0; ni < NI; ++ni)
            bl[ni] = *(const bf16x8*)((const char*)BsL[s] + boff + ni * 1024);
        #pragma unroll
        for (int mi = 0; mi < MI; ++mi)
            #pragma unroll
            for (int ni = 0; ni < NI; ++ni)
                acc[mi][ni] = MFMA16(ah[mi], bl[ni], acc[mi][ni]);

        bf16x8 al[MI];
        #pragma unroll
        for (int mi = 0; mi < MI; ++mi)
            al[mi] = *(const bf16x8*)((const char*)AsL[s] + aoff + mi * 1024);
        #pragma unroll
        for (int mi = 0; mi < MI; ++mi)
            #pragma unroll
            for (int ni = 0; ni < NI; ++ni)
                acc[mi][ni] = MFMA16(al[mi], bh[ni], acc[mi][ni]);
        __builtin_amdgcn_s_setprio(0);
    }

    // ---- epilogue ----
    #pragma unroll
    for (int ni = 0; ni < NI; ++ni) {
        const int n = n0 + wn * (NI * 16) + ni * 16 + l16;
        const float bv = bias[n];
        if constexpr (EPI) {
            const int tq  = n / HID;
            const int rem = n - tq * HID;
            const int h   = rem / HD;
            const int d   = rem - h * HD;
            #pragma unroll
            for (int mi = 0; mi < MI; ++mi) {
                const int mb = m0 + wm * (MI * 16) + mi * 16 + quad * 4;
                if (tq == 2) {
                    ushort4 pv;
                    pv.x = f2bf(acc[mi][ni][0] + bv);
                    pv.y = f2bf(acc[mi][ni][1] + bv);
                    pv.z = f2bf(acc[mi][ni][2] + bv);
                    pv.w = f2bf(acc[mi][ni][3] + bv);
                    *(ushort4*)&ov[((size_t)h * HD + d) * S_LEN + mb] = pv;
                } else {
                    uint16_t* dst = (tq == 0) ? oq : ok;
                    #pragma unroll
                    for (int r = 0; r < 4; ++r)
                        dst[((size_t)h * S_LEN + (mb + r)) * HD + d] =
                            f2bf(acc[mi][ni][r] + bv);
                }
            }
        } else {
            #pragma unroll
            for (int mi = 0; mi < MI; ++mi) {
                const int mb = m0 + wm * (MI * 16) + mi * 16 + quad * 4;
                #pragma unroll
                for (int r = 0; r < 4; ++r)
                    oF[(size_t)(mb + r) * ND + n] = acc[mi][ni][r] + bv;
            }
        }
    }
}

// ---------------- rope: vectorized, one thread per (h,s) row of 80 ----------------
__global__ __launch_bounds__(256)
void rope_kernel(uint16_t* __restrict__ qb, uint16_t* __restrict__ kb,
                 const float* __restrict__ cosb, const float* __restrict__ sinb)
{
    const int t = blockIdx.x * 256 + threadIdx.x;    // h*S_LEN + s
    const int s = t & (S_LEN - 1);
    uint16_t* qr = qb + (size_t)t * HD;
    uint16_t* kr = kb + (size_t)t * HD;
    const float* cr = cosb + (size_t)s * HD;
    const float* sr = sinb + (size_t)s * HD;
    #pragma unroll
    for (int ch = 0; ch < 5; ++ch) {
        const int d = ch * 8;
        u16x8 q1 = *(const u16x8*)(qr + d);
        u16x8 q2 = *(const u16x8*)(qr + d + 40);
        u16x8 k1 = *(const u16x8*)(kr + d);
        u16x8 k2 = *(const u16x8*)(kr + d + 40);
        float c1[8], c2[8], s1[8], s2[8];
        *(float4*)&c1[0] = *(const float4*)(cr + d);
        *(float4*)&c1[4] = *(const float4*)(cr + d + 4);
        *(float4*)&c2[0] = *(const float4*)(cr + d + 40);
        *(float4*)&c2[4] = *(const float4*)(cr + d + 44);
        *(float4*)&s1[0] = *(const float4*)(sr + d);
        *(float4*)&s1[4] = *(const float4*)(sr + d + 4);
        *(float4*)&s2[0] = *(const float4*)(sr + d + 40);
        *(float4*)&s2[4] = *(const float4*)(sr + d + 44);
        u16x8 o1, o2, p1, p2;
        #pragma unroll
        for (int j = 0; j < 8; ++j) {
            float q1f = bf2f((uint16_t)q1[j]), q2f = bf2f((uint16_t)q2[j]);
            o1[j] = f2bf(q1f * c1[j] - q2f * s1[j]);
            o2[j] = f2bf(q2f * c2[j] + q1f * s2[j]);
            float k1f = bf2f((uint16_t)k1[j]), k2f = bf2f((uint16_t)k2[j]);
            p1[j] = f2bf(k1f * c1[j] - k2f * s1[j]);
            p2[j] = f2bf(k2f * c2[j] + k1f * s2[j]);
        }
        *(u16x8*)(qr + d)      = o1;
        *(u16x8*)(qr + d + 40) = o2;
        *(u16x8*)(kr + d)      = p1;
        *(u16x8*)(kr + d + 40) = p2;
    }
}

// ---------------- MFMA flash attention, BQ=256, 8 waves, conflict-free LDS ------------
// (unchanged from the passing round-4 build)
#define BQ 256
#define BK 64

__device__ __forceinline__ void kstage(const char* kg, char* dst, int w, int lane)
{
    int p = w * 1024 + lane * 16;
    {   // regA: phys (row, sl) holds global d-slot sl^(row&7)
        int row = p >> 7;
        int sl  = (p >> 4) & 7;
        glds16(kg + row * 160 + ((sl ^ (row & 7)) << 4), dst + p);
    }
    int p2 = p + 8192;
    if (p2 < 10240) {   // regB: waves 0,1; identity mapping, d-slots 8,9
        int q   = p2 - 8192;
        int row = q >> 5;
        int sl  = (q >> 4) & 1;
        glds16(kg + row * 160 + 128 + (sl << 4), dst + p2);
    }
}

__global__ __launch_bounds__(512, 4)
void attn_kernel(const uint16_t* __restrict__ qb, const uint16_t* __restrict__ kb,
                 const uint16_t* __restrict__ vt,
                 uint16_t* __restrict__ abh, uint16_t* __restrict__ abl)
{
    __shared__ __align__(16) uint16_t smemA[BQ * HD];     // 40960 B: Q staging, then psw
    __shared__ __align__(16) uint16_t ksm[2][BK * HD];    // K tiles dbuf (regA+regB)
    __shared__ __align__(16) uint16_t vsm[HD * BK];       // V tile [d][k], swizzled

    const int tid  = threadIdx.x;
    const int w    = tid >> 6;
    const int lane = tid & 63;
    const int quad = lane >> 4;
    const int l16  = lane & 15;

    const int qt = blockIdx.x;
    const int h  = blockIdx.y;
    const int c  = blockIdx.z;
    const int q0 = c * LCH + qt * BQ;

    uint16_t (*psw)[68] = (uint16_t(*)[68])smemA + w * 32;

    {
        const char* qg = (const char*)(qb + ((size_t)h * S_LEN + q0) * HD);
        for (int off = w * 1024; off < BQ * HD * 2; off += 8192)
            glds16(qg + off + lane * 16, (char*)smemA + off);
    }
    __syncthreads();

    bf16x8 qfr[2][3];
    #pragma unroll
    for (int mi = 0; mi < 2; ++mi) {
        const int row = w * 32 + mi * 16 + l16;
        qfr[mi][0] = *(const bf16x8*)&smemA[row * HD + quad * 8];
        qfr[mi][1] = *(const bf16x8*)&smemA[row * HD + 32 + quad * 8];
        bf16x8 z = {0, 0, 0, 0, 0, 0, 0, 0};
        qfr[mi][2] = (quad < 2) ? *(const bf16x8*)&smemA[row * HD + 64 + quad * 8] : z;
    }

    bf16x8 vf5;
    {
        short o = (l16 == 0) ? (short)0x3F80 : (short)0;
        vf5 = (bf16x8){o, o, o, o, o, o, o, o};
    }

    f32x4 Oacc[2][6];
    #pragma unroll
    for (int mi = 0; mi < 2; ++mi)
        #pragma unroll
        for (int d = 0; d < 6; d++) Oacc[mi][d] = (f32x4){0.f, 0.f, 0.f, 0.f};

    const float C2 = 0.11180339887498949f * 1.4426950408889634f;  // 1/sqrt(80)*log2e
    const char* kg0 = (const char*)(kb + ((size_t)h * S_LEN + c * LCH) * HD);
    const size_t vrow_stride = (size_t)S_LEN * 2;
    const char* vg0 = (const char*)vt + (size_t)h * HD * S_LEN * 2 + (size_t)(c * LCH) * 2;

    kstage(kg0, (char*)&ksm[0][0], w, lane);

    for (int kt = 0; kt < LCH / BK; ++kt) {
        __syncthreads();   // barrier A: K(kt) staged (drain covered by PV(kt-1))

        {
            const char* vg = vg0 + (size_t)(kt * BK) * 2;
            for (int off = w * 1024; off < HD * BK * 2; off += 8192) {
                int o   = off + lane * 16;
                int row = o >> 7;
                int col = o & 127;
                glds16(vg + (size_t)row * vrow_stride + (col ^ ((row & 7) << 4)),
                       (char*)vsm + off);
            }
        }

        const char* ksb = (const char*)&ksm[kt & 1][0];
        #pragma unroll
        for (int ns = 0; ns < 4; ++ns) {
            const int kr = ns * 16 + l16;
            const int sw = (kr & 7) << 4;
            bf16x8 kf0 = *(const bf16x8*)(ksb + kr * 128 + ((quad * 16) ^ sw));
            bf16x8 kf1 = *(const bf16x8*)(ksb + kr * 128 + ((64 + quad * 16) ^ sw));
            bf16x8 z = {0, 0, 0, 0, 0, 0, 0, 0};
            bf16x8 kf2 = (quad < 2)
                ? *(const bf16x8*)(ksb + 8192 + kr * 32 + quad * 16) : z;
            #pragma unroll
            for (int mi = 0; mi < 2; ++mi) {
                f32x4 s = (f32x4){0.f, 0.f, 0.f, 0.f};
                s = MFMA16(kf0, qfr[mi][0], s);
                s = MFMA16(kf1, qfr[mi][1], s);
                s = MFMA16(kf2, qfr[mi][2], s);
                float e0 = exp2f(s[0] * C2);
                float e1 = exp2f(s[1] * C2);
                float e2 = exp2f(s[2] * C2);
                float e3 = exp2f(s[3] * C2);
                *(uint2*)&psw[mi * 16 + l16][ns * 16 + quad * 4] =
                    (uint2){pk2(e0, e1), pk2(e2, e3)};
            }
        }

        __syncthreads();   // barrier B: V(kt) staged (drain covered by QK)

        if (kt + 1 < LCH / BK)
            kstage(kg0 + (size_t)(kt + 1) * BK * HD * 2,
                   (char*)&ksm[(kt + 1) & 1][0], w, lane);

        #pragma unroll
        for (int kc = 0; kc < 2; ++kc) {
            bf16x8 pf[2];
            #pragma unroll
            for (int mi = 0; mi < 2; ++mi) {
                const uint16_t* pp = &psw[mi * 16 + l16][kc * 32 + quad * 8];
                ((uint2*)&pf[mi])[0] = *(const uint2*)(pp);
                ((uint2*)&pf[mi])[1] = *(const uint2*)(pp + 4);
            }
            #pragma unroll
            for (int ds = 0; ds < 5; ++ds) {
                const int vr = ds * 16 + l16;
                bf16x8 vf = *(const bf16x8*)((const char*)vsm + vr * 128 +
                    ((kc * 64 + quad * 16) ^ ((vr & 7) << 4)));
                #pragma unroll
                for (int mi = 0; mi < 2; ++mi)
                    Oacc[mi][ds] = MFMA16(pf[mi], vf, Oacc[mi][ds]);
            }
            #pragma unroll
            for (int mi = 0; mi < 2; ++mi)
                Oacc[mi][5] = MFMA16(pf[mi], vf5, Oacc[mi][5]);
        }
    }

    #pragma unroll
    for (int mi = 0; mi < 2; ++mi)
        #pragma unroll
        for (int r = 0; r < 4; ++r) {
            float l = __shfl(Oacc[mi][5][r], lane & 48);
            float inv = 1.f / l;
            const int srow = q0 + w * 32 + mi * 16 + quad * 4 + r;
            const size_t rowbase = (size_t)srow * HID + h * HD;
            #pragma unroll
            for (int ds = 0; ds < 5; ++ds) {
                float f = Oacc[mi][ds][r] * inv;
                uint16_t hi = f2bf(f);
                abh[rowbase + ds * 16 + l16] = hi;
                abl[rowbase + ds * 16 + l16] = f2bf(f - bf2f(hi));
            }
        }
}

extern "C" void kernel_launch(void* const* d_in, const int* in_sizes, int n_in,
                              void* d_out, int out_size, void* d_ws, size_t ws_size,
                              hipStream_t stream)
{
    const float* x     = (const float*)d_in[0];
    const float* cosb  = (const float*)d_in[1];
    const float* sinb  = (const float*)d_in[2];
    const float* Wqkv  = (const float*)d_in[3];
    const float* bqkv  = (const float*)d_in[4];
    const float* Wproj = (const float*)d_in[5];
    const float* bproj = (const float*)d_in[6];
    float* out = (float*)d_out;

    const size_t E = (size_t)NH * S_LEN * HD;   // 10,485,760 (= S*HID)
    uint16_t* qb  = (uint16_t*)d_ws;            // [h][s][80]
    uint16_t* kb  = qb + E;                     // [h][s][80]
    uint16_t* vt  = kb + E;                     // [h][80][s]
    uint16_t* xh  = vt + E;                     // x_hi [s][1280]; later ab_hi
    uint16_t* xl  = xh + E;                     // x_lo;           later ab_lo
    uint16_t* wth = xl + E;                     // W^T hi
    uint16_t* wtl = wth + (size_t)3 * HID * HID;

    xsplit_kernel<<<(S_LEN * HID) / (256 * 4), 256, 0, stream>>>(x, xh, xl);
    wsplit_kernel<3 * HID><<<dim3(3 * HID / 32, HID / 32), 256, 0, stream>>>(Wqkv, wth, wtl);
    // QKV: BN=256, waves 2x4, single-barrier loop, XCD swizzle (480 blocks)
    gemm1b<3 * HID, 256, 4, 1>
        <<<dim3(3 * HID / 256, S_LEN / 256), 512, 0, stream>>>(
        xh, xl, wth, wtl, bqkv, nullptr, qb, kb, vt);
    rope_kernel<<<(NH * S_LEN) / 256, 256, 0, stream>>>(qb, kb, cosb, sinb);
    attn_kernel<<<dim3(LCH / BQ, NH, NCH), 512, 0, stream>>>(qb, kb, vt, xh, xl);
    wsplit_kernel<HID><<<dim3(HID / 32, HID / 32), 256, 0, stream>>>(Wproj, wth, wtl);
    // proj: BN=160, waves 4x2, single-barrier loop, XCD swizzle (256 blocks)
    gemm1b<HID, 160, 2, 0>
        <<<dim3(HID / 160, S_LEN / 256), 512, 0, stream>>>(
        xh, xl, wth, wtl, bproj, out, nullptr, nullptr, nullptr);
}

// Round 6
// 525.049 us; speedup vs baseline: 1.0768x; 1.0768x over previous
//
#include <hip/hip_runtime.h>
#include <math.h>
#include <stdint.h>

#define S_LEN 8192
#define HID   1280
#define NH    16
#define HD    80
#define LCH   1024
#define NCH   8

typedef __attribute__((ext_vector_type(8))) short bf16x8;
typedef __attribute__((ext_vector_type(8))) unsigned short u16x8;
typedef __attribute__((ext_vector_type(4))) float f32x4;

__device__ __forceinline__ uint16_t f2bf(float f) {
    union { float f; uint32_t u; } v; v.f = f;
    uint32_t r = v.u + 0x7FFF + ((v.u >> 16) & 1);   // RNE
    return (uint16_t)(r >> 16);
}
__device__ __forceinline__ float bf2f(uint16_t h) {
    union { uint32_t u; float f; } v; v.u = ((uint32_t)h) << 16;
    return v.f;
}
__device__ __forceinline__ uint32_t pk2(float a, float b) {   // trunc-bf16 pair pack
    union { float f; uint32_t u; } x, y; x.f = a; y.f = b;
    return (x.u >> 16) | (y.u & 0xFFFF0000u);
}

__device__ __forceinline__ void glds16(const void* g, void* l) {
    __builtin_amdgcn_global_load_lds(
        (const __attribute__((address_space(1))) uint32_t*)g,
        (__attribute__((address_space(3))) uint32_t*)l,
        16, 0, 0);
}

#define MFMA16(a, b, c) __builtin_amdgcn_mfma_f32_16x16x32_bf16(a, b, c, 0, 0, 0)
#define SB()  __builtin_amdgcn_sched_barrier(0)
#define BAR() __builtin_amdgcn_s_barrier()

template<int N> __device__ __forceinline__ void vmwait() {
    if constexpr (N == 0) asm volatile("s_waitcnt vmcnt(0)" ::: "memory");
    else if constexpr (N == 2) asm volatile("s_waitcnt vmcnt(2)" ::: "memory");
    else if constexpr (N == 4) asm volatile("s_waitcnt vmcnt(4)" ::: "memory");
}

// stage one [rows x 32] bf16 K-tile (nbytes = rows*64) into LDS, linear dest,
// global source pre-swizzled per lane so the ds_read-side XOR swizzle matches.
// chunk advance: 1024 B LDS <-> 16 rows * 2560 B global = off*40.
__device__ __forceinline__ void stage_tile(const char* gsrc, char* dst, int w,
                                           int kt, int nbytes)
{
    const char* sp = gsrc + (size_t)kt * 64;
    int off = w * 1024;
    glds16(sp + (size_t)off * 40, dst + off);
    off += 8192;
    if (off < nbytes) glds16(sp + (size_t)off * 40, dst + off);
}

// ---------------- prepass: split x fp32 -> hi/lo bf16 (same layout) ----------------
__global__ __launch_bounds__(256)
void xsplit_kernel(const float* __restrict__ x, uint16_t* __restrict__ xh,
                   uint16_t* __restrict__ xl)
{
    int idx = (blockIdx.x * 256 + threadIdx.x) * 4;
    float4 v = *(const float4*)(x + idx);
    ushort4 hi, lo;
    hi.x = f2bf(v.x); lo.x = f2bf(v.x - bf2f(hi.x));
    hi.y = f2bf(v.y); lo.y = f2bf(v.y - bf2f(hi.y));
    hi.z = f2bf(v.z); lo.z = f2bf(v.z - bf2f(hi.z));
    hi.w = f2bf(v.w); lo.w = f2bf(v.w - bf2f(hi.w));
    *(ushort4*)(xh + idx) = hi;
    *(ushort4*)(xl + idx) = lo;
}

// ---------------- prepass: W [1280][ND] fp32 -> W^T [ND][1280] hi/lo bf16 ----------------
template<int ND>
__global__ __launch_bounds__(256)
void wsplit_kernel(const float* __restrict__ W, uint16_t* __restrict__ Wth,
                   uint16_t* __restrict__ Wtl)
{
    __shared__ float t[32][33];
    const int tid = threadIdx.x;
    const int n0 = blockIdx.x * 32;
    const int k0 = blockIdx.y * 32;
    for (int i = tid; i < 1024; i += 256) {
        int r = i >> 5, c = i & 31;
        t[r][c] = W[(size_t)(k0 + r) * ND + n0 + c];
    }
    __syncthreads();
    for (int i = tid; i < 1024; i += 256) {
        int r = i >> 5, c = i & 31;          // r: n offset, c: k offset
        float f = t[c][r];
        uint16_t hi = f2bf(f);
        size_t o = (size_t)(n0 + r) * HID + k0 + c;
        Wth[o] = hi;
        Wtl[o] = f2bf(f - bf2f(hi));
    }
}

// ---------------- split-bf16 MFMA GEMM, 3-phase counted-vmcnt pipeline (schedule B) ----
// P1 {read ah,bh | stage Ah,Bh(t+1) | vmcnt(W1) | bar | MFMA hh}
// P2 {read bl    | stage Bl,Al(t+1) |            bar | MFMA hl}
// P3 {read al    |                  | vmcnt(W1) | bar | MFMA lh}
// Every buffer's landing is enforced one full phase before its first ds_read.
// W1 derivation (per-wave FIFO): at each wait point the loads that must land are
// exactly the OLDER group; W1 = min over waves of the newer group's size.
// QKV (BM=256,BN=256): 4 loads/group all waves -> W1=4. proj (BM=128,BN=160):
// P1 group = {Ah:1, Bh:1-2}, P2 group = {Bl:1-2, Al:1} -> W1=2.
template<int BM, int ND, int BN, int NWM, int NWN, int EPI, int W1>
__global__ __launch_bounds__(512, 2)
void gemm8p(const uint16_t* __restrict__ Ahp, const uint16_t* __restrict__ Alp,
            const uint16_t* __restrict__ Bth, const uint16_t* __restrict__ Btl,
            const float* __restrict__ bias, float* __restrict__ oF,
            uint16_t* __restrict__ oq, uint16_t* __restrict__ ok,
            uint16_t* __restrict__ ov)
{
    constexpr int MI  = BM / (NWM * 16);
    constexpr int NI  = BN / (NWN * 16);
    constexpr int ABYTES = BM * 64;
    constexpr int BBYTES = BN * 64;
    constexpr int NT = HID / 32;             // 40 K-tiles
    static_assert(NWM * NWN == 8, "8 waves");
    static_assert(BM % (NWM * 16) == 0 && BN % (NWN * 16) == 0, "tile split");

    __shared__ __align__(1024) uint16_t AsH[2][ABYTES / 2];
    __shared__ __align__(1024) uint16_t AsL[2][ABYTES / 2];
    __shared__ __align__(1024) uint16_t BsH[2][BBYTES / 2];
    __shared__ __align__(1024) uint16_t BsL[2][BBYTES / 2];

    const int tid  = threadIdx.x;
    const int w    = tid >> 6;
    const int lane = tid & 63;
    const int quad = lane >> 4;
    const int l16  = lane & 15;
    const int wm   = w / NWN;
    const int wn   = w % NWN;

    const int n0 = blockIdx.x * BN;
    const int m0 = blockIdx.y * BM;

    const size_t stg = (size_t)(lane >> 2) * (HID * 2)
                     + (size_t)(((lane & 3) ^ ((lane >> 3) & 3)) << 4);
    const char* gAh = (const char*)Ahp + (size_t)m0 * (HID * 2) + stg;
    const char* gAl = (const char*)Alp + (size_t)m0 * (HID * 2) + stg;
    const char* gBh = (const char*)Bth + (size_t)n0 * (HID * 2) + stg;
    const char* gBl = (const char*)Btl + (size_t)n0 * (HID * 2) + stg;

    const int swz  = (quad ^ ((l16 >> 1) & 3)) << 4;
    const int aoff = (wm * (MI * 16) + l16) * 64 + swz;
    const int boff = (wn * (NI * 16) + l16) * 64 + swz;

    f32x4 acc[MI][NI];
    #pragma unroll
    for (int mi = 0; mi < MI; ++mi)
        #pragma unroll
        for (int ni = 0; ni < NI; ++ni) acc[mi][ni] = (f32x4){0.f, 0.f, 0.f, 0.f};

    // prologue: stage kt=0 in stream order [Ah, Bh, Bl, Al]
    stage_tile(gAh, (char*)AsH[0], w, 0, ABYTES);
    stage_tile(gBh, (char*)BsH[0], w, 0, BBYTES);
    stage_tile(gBl, (char*)BsL[0], w, 0, BBYTES);
    stage_tile(gAl, (char*)AsL[0], w, 0, ABYTES);
    SB(); vmwait<W1>(); BAR(); SB();

    for (int kt = 0; kt < NT - 1; ++kt) {
        const int s = kt & 1, t = s ^ 1;
        bf16x8 ah[MI], bh[NI];

        // ---- P1: hh ----
        #pragma unroll
        for (int mi = 0; mi < MI; ++mi)
            ah[mi] = *(const bf16x8*)((const char*)AsH[s] + aoff + mi * 1024);
        #pragma unroll
        for (int ni = 0; ni < NI; ++ni)
            bh[ni] = *(const bf16x8*)((const char*)BsH[s] + boff + ni * 1024);
        stage_tile(gAh, (char*)AsH[t], w, kt + 1, ABYTES);
        stage_tile(gBh, (char*)BsH[t], w, kt + 1, BBYTES);
        SB(); vmwait<W1>(); BAR(); SB();
        __builtin_amdgcn_s_setprio(1);
        #pragma unroll
        for (int mi = 0; mi < MI; ++mi)
            #pragma unroll
            for (int ni = 0; ni < NI; ++ni)
                acc[mi][ni] = MFMA16(ah[mi], bh[ni], acc[mi][ni]);
        __builtin_amdgcn_s_setprio(0);

        // ---- P2: hl (ah live) ----
        bf16x8 bl[NI];
        #pragma unroll
        for (int ni = 0; ni < NI; ++ni)
            bl[ni] = *(const bf16x8*)((const char*)BsL[s] + boff + ni * 1024);
        stage_tile(gBl, (char*)BsL[t], w, kt + 1, BBYTES);
        stage_tile(gAl, (char*)AsL[t], w, kt + 1, ABYTES);
        SB(); BAR(); SB();
        __builtin_amdgcn_s_setprio(1);
        #pragma unroll
        for (int mi = 0; mi < MI; ++mi)
            #pragma unroll
            for (int ni = 0; ni < NI; ++ni)
                acc[mi][ni] = MFMA16(ah[mi], bl[ni], acc[mi][ni]);
        __builtin_amdgcn_s_setprio(0);

        // ---- P3: lh (bh live) ----
        bf16x8 al[MI];
        #pragma unroll
        for (int mi = 0; mi < MI; ++mi)
            al[mi] = *(const bf16x8*)((const char*)AsL[s] + aoff + mi * 1024);
        SB(); vmwait<W1>(); BAR(); SB();
        __builtin_amdgcn_s_setprio(1);
        #pragma unroll
        for (int mi = 0; mi < MI; ++mi)
            #pragma unroll
            for (int ni = 0; ni < NI; ++ni)
                acc[mi][ni] = MFMA16(al[mi], bh[ni], acc[mi][ni]);
        __builtin_amdgcn_s_setprio(0);
    }

    // ---- peeled last K-tile ----
    {
        const int s = (NT - 1) & 1;
        bf16x8 ah[MI], bh[NI];
        #pragma unroll
        for (int mi = 0; mi < MI; ++mi)
            ah[mi] = *(const bf16x8*)((const char*)AsH[s] + aoff + mi * 1024);
        #pragma unroll
        for (int ni = 0; ni < NI; ++ni)
            bh[ni] = *(const bf16x8*)((const char*)BsH[s] + boff + ni * 1024);
        SB(); vmwait<0>(); BAR(); SB();
        __builtin_amdgcn_s_setprio(1);
        #pragma unroll
        for (int mi = 0; mi < MI; ++mi)
            #pragma unroll
            for (int ni = 0; ni < NI; ++ni)
                acc[mi][ni] = MFMA16(ah[mi], bh[ni], acc[mi][ni]);
        __builtin_amdgcn_s_setprio(0);

        bf16x8 bl[NI];
        #pragma unroll
        for (int ni = 0; ni < NI; ++ni)
            bl[ni] = *(const bf16x8*)((const char*)BsL[s] + boff + ni * 1024);
        #pragma unroll
        for (int mi = 0; mi < MI; ++mi)
            #pragma unroll
            for (int ni = 0; ni < NI; ++ni)
                acc[mi][ni] = MFMA16(ah[mi], bl[ni], acc[mi][ni]);

        bf16x8 al[MI];
        #pragma unroll
        for (int mi = 0; mi < MI; ++mi)
            al[mi] = *(const bf16x8*)((const char*)AsL[s] + aoff + mi * 1024);
        #pragma unroll
        for (int mi = 0; mi < MI; ++mi)
            #pragma unroll
            for (int ni = 0; ni < NI; ++ni)
                acc[mi][ni] = MFMA16(al[mi], bh[ni], acc[mi][ni]);
    }

    // ---- epilogue ----
    #pragma unroll
    for (int ni = 0; ni < NI; ++ni) {
        const int n = n0 + wn * (NI * 16) + ni * 16 + l16;
        const float bv = bias[n];
        if constexpr (EPI) {
            const int tq  = n / HID;
            const int rem = n - tq * HID;
            const int h   = rem / HD;
            const int d   = rem - h * HD;
            #pragma unroll
            for (int mi = 0; mi < MI; ++mi) {
                const int mb = m0 + wm * (MI * 16) + mi * 16 + quad * 4;
                if (tq == 2) {
                    ushort4 pv;
                    pv.x = f2bf(acc[mi][ni][0] + bv);
                    pv.y = f2bf(acc[mi][ni][1] + bv);
                    pv.z = f2bf(acc[mi][ni][2] + bv);
                    pv.w = f2bf(acc[mi][ni][3] + bv);
                    *(ushort4*)&ov[((size_t)h * HD + d) * S_LEN + mb] = pv;
                } else {
                    uint16_t* dst = (tq == 0) ? oq : ok;
                    #pragma unroll
                    for (int r = 0; r < 4; ++r)
                        dst[((size_t)h * S_LEN + (mb + r)) * HD + d] =
                            f2bf(acc[mi][ni][r] + bv);
                }
            }
        } else {
            #pragma unroll
            for (int mi = 0; mi < MI; ++mi) {
                const int mb = m0 + wm * (MI * 16) + mi * 16 + quad * 4;
                #pragma unroll
                for (int r = 0; r < 4; ++r)
                    oF[(size_t)(mb + r) * ND + n] = acc[mi][ni][r] + bv;
            }
        }
    }
}

// ---------------- rope: vectorized, one thread per (h,s) row of 80 ----------------
__global__ __launch_bounds__(256)
void rope_kernel(uint16_t* __restrict__ qb, uint16_t* __restrict__ kb,
                 const float* __restrict__ cosb, const float* __restrict__ sinb)
{
    const int t = blockIdx.x * 256 + threadIdx.x;    // h*S_LEN + s
    const int s = t & (S_LEN - 1);
    uint16_t* qr = qb + (size_t)t * HD;
    uint16_t* kr = kb + (size_t)t * HD;
    const float* cr = cosb + (size_t)s * HD;
    const float* sr = sinb + (size_t)s * HD;
    #pragma unroll
    for (int ch = 0; ch < 5; ++ch) {
        const int d = ch * 8;
        u16x8 q1 = *(const u16x8*)(qr + d);
        u16x8 q2 = *(const u16x8*)(qr + d + 40);
        u16x8 k1 = *(const u16x8*)(kr + d);
        u16x8 k2 = *(const u16x8*)(kr + d + 40);
        float c1[8], c2[8], s1[8], s2[8];
        *(float4*)&c1[0] = *(const float4*)(cr + d);
        *(float4*)&c1[4] = *(const float4*)(cr + d + 4);
        *(float4*)&c2[0] = *(const float4*)(cr + d + 40);
        *(float4*)&c2[4] = *(const float4*)(cr + d + 44);
        *(float4*)&s1[0] = *(const float4*)(sr + d);
        *(float4*)&s1[4] = *(const float4*)(sr + d + 4);
        *(float4*)&s2[0] = *(const float4*)(sr + d + 40);
        *(float4*)&s2[4] = *(const float4*)(sr + d + 44);
        u16x8 o1, o2, p1, p2;
        #pragma unroll
        for (int j = 0; j < 8; ++j) {
            float q1f = bf2f((uint16_t)q1[j]), q2f = bf2f((uint16_t)q2[j]);
            o1[j] = f2bf(q1f * c1[j] - q2f * s1[j]);
            o2[j] = f2bf(q2f * c2[j] + q1f * s2[j]);
            float k1f = bf2f((uint16_t)k1[j]), k2f = bf2f((uint16_t)k2[j]);
            p1[j] = f2bf(k1f * c1[j] - k2f * s1[j]);
            p2[j] = f2bf(k2f * c2[j] + k1f * s2[j]);
        }
        *(u16x8*)(qr + d)      = o1;
        *(u16x8*)(qr + d + 40) = o2;
        *(u16x8*)(kr + d)      = p1;
        *(u16x8*)(kr + d + 40) = p2;
    }
}

// ---------------- MFMA flash attention, BQ=256, 8 waves, conflict-free LDS ------------
// (unchanged from the passing round-4 build)
#define BQ 256
#define BK 64

__device__ __forceinline__ void kstage(const char* kg, char* dst, int w, int lane)
{
    int p = w * 1024 + lane * 16;
    {   // regA: phys (row, sl) holds global d-slot sl^(row&7)
        int row = p >> 7;
        int sl  = (p >> 4) & 7;
        glds16(kg + row * 160 + ((sl ^ (row & 7)) << 4), dst + p);
    }
    int p2 = p + 8192;
    if (p2 < 10240) {   // regB: waves 0,1; identity mapping, d-slots 8,9
        int q   = p2 - 8192;
        int row = q >> 5;
        int sl  = (q >> 4) & 1;
        glds16(kg + row * 160 + 128 + (sl << 4), dst + p2);
    }
}

__global__ __launch_bounds__(512, 4)
void attn_kernel(const uint16_t* __restrict__ qb, const uint16_t* __restrict__ kb,
                 const uint16_t* __restrict__ vt,
                 uint16_t* __restrict__ abh, uint16_t* __restrict__ abl)
{
    __shared__ __align__(16) uint16_t smemA[BQ * HD];     // 40960 B: Q staging, then psw
    __shared__ __align__(16) uint16_t ksm[2][BK * HD];    // K tiles dbuf (regA+regB)
    __shared__ __align__(16) uint16_t vsm[HD * BK];       // V tile [d][k], swizzled

    const int tid  = threadIdx.x;
    const int w    = tid >> 6;
    const int lane = tid & 63;
    const int quad = lane >> 4;
    const int l16  = lane & 15;

    const int qt = blockIdx.x;
    const int h  = blockIdx.y;
    const int c  = blockIdx.z;
    const int q0 = c * LCH + qt * BQ;

    uint16_t (*psw)[68] = (uint16_t(*)[68])smemA + w * 32;

    {
        const char* qg = (const char*)(qb + ((size_t)h * S_LEN + q0) * HD);
        for (int off = w * 1024; off < BQ * HD * 2; off += 8192)
            glds16(qg + off + lane * 16, (char*)smemA + off);
    }
    __syncthreads();

    bf16x8 qfr[2][3];
    #pragma unroll
    for (int mi = 0; mi < 2; ++mi) {
        const int row = w * 32 + mi * 16 + l16;
        qfr[mi][0] = *(const bf16x8*)&smemA[row * HD + quad * 8];
        qfr[mi][1] = *(const bf16x8*)&smemA[row * HD + 32 + quad * 8];
        bf16x8 z = {0, 0, 0, 0, 0, 0, 0, 0};
        qfr[mi][2] = (quad < 2) ? *(const bf16x8*)&smemA[row * HD + 64 + quad * 8] : z;
    }

    bf16x8 vf5;
    {
        short o = (l16 == 0) ? (short)0x3F80 : (short)0;
        vf5 = (bf16x8){o, o, o, o, o, o, o, o};
    }

    f32x4 Oacc[2][6];
    #pragma unroll
    for (int mi = 0; mi < 2; ++mi)
        #pragma unroll
        for (int d = 0; d < 6; d++) Oacc[mi][d] = (f32x4){0.f, 0.f, 0.f, 0.f};

    const float C2 = 0.11180339887498949f * 1.4426950408889634f;  // 1/sqrt(80)*log2e
    const char* kg0 = (const char*)(kb + ((size_t)h * S_LEN + c * LCH) * HD);
    const size_t vrow_stride = (size_t)S_LEN * 2;
    const char* vg0 = (const char*)vt + (size_t)h * HD * S_LEN * 2 + (size_t)(c * LCH) * 2;

    kstage(kg0, (char*)&ksm[0][0], w, lane);

    for (int kt = 0; kt < LCH / BK; ++kt) {
        __syncthreads();   // barrier A: K(kt) staged (drain covered by PV(kt-1))

        {
            const char* vg = vg0 + (size_t)(kt * BK) * 2;
            for (int off = w * 1024; off < HD * BK * 2; off += 8192) {
                int o   = off + lane * 16;
                int row = o >> 7;
                int col = o & 127;
                glds16(vg + (size_t)row * vrow_stride + (col ^ ((row & 7) << 4)),
                       (char*)vsm + off);
            }
        }

        const char* ksb = (const char*)&ksm[kt & 1][0];
        #pragma unroll
        for (int ns = 0; ns < 4; ++ns) {
            const int kr = ns * 16 + l16;
            const int sw = (kr & 7) << 4;
            bf16x8 kf0 = *(const bf16x8*)(ksb + kr * 128 + ((quad * 16) ^ sw));
            bf16x8 kf1 = *(const bf16x8*)(ksb + kr * 128 + ((64 + quad * 16) ^ sw));
            bf16x8 z = {0, 0, 0, 0, 0, 0, 0, 0};
            bf16x8 kf2 = (quad < 2)
                ? *(const bf16x8*)(ksb + 8192 + kr * 32 + quad * 16) : z;
            #pragma unroll
            for (int mi = 0; mi < 2; ++mi) {
                f32x4 s = (f32x4){0.f, 0.f, 0.f, 0.f};
                s = MFMA16(kf0, qfr[mi][0], s);
                s = MFMA16(kf1, qfr[mi][1], s);
                s = MFMA16(kf2, qfr[mi][2], s);
                float e0 = exp2f(s[0] * C2);
                float e1 = exp2f(s[1] * C2);
                float e2 = exp2f(s[2] * C2);
                float e3 = exp2f(s[3] * C2);
                *(uint2*)&psw[mi * 16 + l16][ns * 16 + quad * 4] =
                    (uint2){pk2(e0, e1), pk2(e2, e3)};
            }
        }

        __syncthreads();   // barrier B: V(kt) staged (drain covered by QK)

        if (kt + 1 < LCH / BK)
            kstage(kg0 + (size_t)(kt + 1) * BK * HD * 2,
                   (char*)&ksm[(kt + 1) & 1][0], w, lane);

        #pragma unroll
        for (int kc = 0; kc < 2; ++kc) {
            bf16x8 pf[2];
            #pragma unroll
            for (int mi = 0; mi < 2; ++mi) {
                const uint16_t* pp = &psw[mi * 16 + l16][kc * 32 + quad * 8];
                ((uint2*)&pf[mi])[0] = *(const uint2*)(pp);
                ((uint2*)&pf[mi])[1] = *(const uint2*)(pp + 4);
            }
            #pragma unroll
            for (int ds = 0; ds < 5; ++ds) {
                const int vr = ds * 16 + l16;
                bf16x8 vf = *(const bf16x8*)((const char*)vsm + vr * 128 +
                    ((kc * 64 + quad * 16) ^ ((vr & 7) << 4)));
                #pragma unroll
                for (int mi = 0; mi < 2; ++mi)
                    Oacc[mi][ds] = MFMA16(pf[mi], vf, Oacc[mi][ds]);
            }
            #pragma unroll
            for (int mi = 0; mi < 2; ++mi)
                Oacc[mi][5] = MFMA16(pf[mi], vf5, Oacc[mi][5]);
        }
    }

    #pragma unroll
    for (int mi = 0; mi < 2; ++mi)
        #pragma unroll
        for (int r = 0; r < 4; ++r) {
            float l = __shfl(Oacc[mi][5][r], lane & 48);
            float inv = 1.f / l;
            const int srow = q0 + w * 32 + mi * 16 + quad * 4 + r;
            const size_t rowbase = (size_t)srow * HID + h * HD;
            #pragma unroll
            for (int ds = 0; ds < 5; ++ds) {
                float f = Oacc[mi][ds][r] * inv;
                uint16_t hi = f2bf(f);
                abh[rowbase + ds * 16 + l16] = hi;
                abl[rowbase + ds * 16 + l16] = f2bf(f - bf2f(hi));
            }
        }
}

extern "C" void kernel_launch(void* const* d_in, const int* in_sizes, int n_in,
                              void* d_out, int out_size, void* d_ws, size_t ws_size,
                              hipStream_t stream)
{
    const float* x     = (const float*)d_in[0];
    const float* cosb  = (const float*)d_in[1];
    const float* sinb  = (const float*)d_in[2];
    const float* Wqkv  = (const float*)d_in[3];
    const float* bqkv  = (const float*)d_in[4];
    const float* Wproj = (const float*)d_in[5];
    const float* bproj = (const float*)d_in[6];
    float* out = (float*)d_out;

    const size_t E = (size_t)NH * S_LEN * HD;   // 10,485,760 (= S*HID)
    uint16_t* qb  = (uint16_t*)d_ws;            // [h][s][80]
    uint16_t* kb  = qb + E;                     // [h][s][80]
    uint16_t* vt  = kb + E;                     // [h][80][s]
    uint16_t* xh  = vt + E;                     // x_hi [s][1280]; later ab_hi
    uint16_t* xl  = xh + E;                     // x_lo;           later ab_lo
    uint16_t* wth = xl + E;                     // W^T hi
    uint16_t* wtl = wth + (size_t)3 * HID * HID;

    xsplit_kernel<<<(S_LEN * HID) / (256 * 4), 256, 0, stream>>>(x, xh, xl);
    wsplit_kernel<3 * HID><<<dim3(3 * HID / 32, HID / 32), 256, 0, stream>>>(Wqkv, wth, wtl);
    // QKV: BM=256, BN=256, waves 2x4, schedule B, W1=4  (known-good R4 config)
    gemm8p<256, 3 * HID, 256, 2, 4, 1, 4>
        <<<dim3(3 * HID / 256, S_LEN / 256), 512, 0, stream>>>(
        xh, xl, wth, wtl, bqkv, nullptr, qb, kb, vt);
    rope_kernel<<<(NH * S_LEN) / 256, 256, 0, stream>>>(qb, kb, cosb, sinb);
    attn_kernel<<<dim3(LCH / BQ, NH, NCH), 512, 0, stream>>>(qb, kb, vt, xh, xl);
    wsplit_kernel<HID><<<dim3(HID / 32, HID / 32), 256, 0, stream>>>(Wproj, wth, wtl);
    // proj: BM=128, BN=160 -> 512 blocks (2/CU), waves 4x2, schedule B, W1=2
    gemm8p<128, HID, 160, 4, 2, 0, 2>
        <<<dim3(HID / 160, S_LEN / 128), 512, 0, stream>>>(
        xh, xl, wth, wtl, bproj, out, nullptr, nullptr, nullptr);
}

// Round 7
// 524.599 us; speedup vs baseline: 1.0777x; 1.0009x over previous
//
#include <hip/hip_runtime.h>
#include <math.h>
#include <stdint.h>

#define S_LEN 8192
#define HID   1280
#define NH    16
#define HD    80
#define LCH   1024
#define NCH   8

typedef __attribute__((ext_vector_type(8))) short bf16x8;
typedef __attribute__((ext_vector_type(8))) unsigned short u16x8;
typedef __attribute__((ext_vector_type(4))) float f32x4;

__device__ __forceinline__ uint16_t f2bf(float f) {
    union { float f; uint32_t u; } v; v.f = f;
    uint32_t r = v.u + 0x7FFF + ((v.u >> 16) & 1);   // RNE
    return (uint16_t)(r >> 16);
}
__device__ __forceinline__ float bf2f(uint16_t h) {
    union { uint32_t u; float f; } v; v.u = ((uint32_t)h) << 16;
    return v.f;
}
__device__ __forceinline__ uint32_t pk2(float a, float b) {   // trunc-bf16 pair pack
    union { float f; uint32_t u; } x, y; x.f = a; y.f = b;
    return (x.u >> 16) | (y.u & 0xFFFF0000u);
}

__device__ __forceinline__ void glds16(const void* g, void* l) {
    __builtin_amdgcn_global_load_lds(
        (const __attribute__((address_space(1))) uint32_t*)g,
        (__attribute__((address_space(3))) uint32_t*)l,
        16, 0, 0);
}

#define MFMA16(a, b, c) __builtin_amdgcn_mfma_f32_16x16x32_bf16(a, b, c, 0, 0, 0)
#define SB()  __builtin_amdgcn_sched_barrier(0)
#define BAR() __builtin_amdgcn_s_barrier()

template<int N> __device__ __forceinline__ void vmwait() {
    if constexpr (N == 0) asm volatile("s_waitcnt vmcnt(0)" ::: "memory");
    else if constexpr (N == 2) asm volatile("s_waitcnt vmcnt(2)" ::: "memory");
    else if constexpr (N == 3) asm volatile("s_waitcnt vmcnt(3)" ::: "memory");
    else if constexpr (N == 4) asm volatile("s_waitcnt vmcnt(4)" ::: "memory");
}

// stage one [rows x 32] bf16 K-tile (nbytes = rows*64) into LDS, linear dest,
// global source pre-swizzled per lane so the ds_read-side XOR swizzle matches.
// chunk advance: 1024 B LDS <-> 16 rows * 2560 B global = off*40.
__device__ __forceinline__ void stage_tile(const char* gsrc, char* dst, int w,
                                           int kt, int nbytes)
{
    const char* sp = gsrc + (size_t)kt * 64;
    int off = w * 1024;
    glds16(sp + (size_t)off * 40, dst + off);
    off += 8192;
    if (off < nbytes) glds16(sp + (size_t)off * 40, dst + off);
}

// ---------------- prepass: split x fp32 -> hi/lo bf16 (same layout) ----------------
__global__ __launch_bounds__(256)
void xsplit_kernel(const float* __restrict__ x, uint16_t* __restrict__ xh,
                   uint16_t* __restrict__ xl)
{
    int idx = (blockIdx.x * 256 + threadIdx.x) * 4;
    float4 v = *(const float4*)(x + idx);
    ushort4 hi, lo;
    hi.x = f2bf(v.x); lo.x = f2bf(v.x - bf2f(hi.x));
    hi.y = f2bf(v.y); lo.y = f2bf(v.y - bf2f(hi.y));
    hi.z = f2bf(v.z); lo.z = f2bf(v.z - bf2f(hi.z));
    hi.w = f2bf(v.w); lo.w = f2bf(v.w - bf2f(hi.w));
    *(ushort4*)(xh + idx) = hi;
    *(ushort4*)(xl + idx) = lo;
}

// ---------------- prepass: W [1280][ND] fp32 -> W^T [ND][1280] hi/lo bf16 ----------------
template<int ND>
__global__ __launch_bounds__(256)
void wsplit_kernel(const float* __restrict__ W, uint16_t* __restrict__ Wth,
                   uint16_t* __restrict__ Wtl)
{
    __shared__ float t[32][33];
    const int tid = threadIdx.x;
    const int n0 = blockIdx.x * 32;
    const int k0 = blockIdx.y * 32;
    for (int i = tid; i < 1024; i += 256) {
        int r = i >> 5, c = i & 31;
        t[r][c] = W[(size_t)(k0 + r) * ND + n0 + c];
    }
    __syncthreads();
    for (int i = tid; i < 1024; i += 256) {
        int r = i >> 5, c = i & 31;          // r: n offset, c: k offset
        float f = t[c][r];
        uint16_t hi = f2bf(f);
        size_t o = (size_t)(n0 + r) * HID + k0 + c;
        Wth[o] = hi;
        Wtl[o] = f2bf(f - bf2f(hi));
    }
}

// ---------------- split-bf16 MFMA GEMM, 3-phase counted-vmcnt pipeline (schedule B) ----
// P1 {read ah,bh | stage Ah,Bh(t+1) | vmcnt(W1) | bar | MFMA hh}
// P2 {read bl    | stage Bl,Al(t+1) |            bar | MFMA hl}
// P3 {read al    |                  | vmcnt(W1) | bar | MFMA lh}
// Every buffer's landing is enforced one full phase before its first ds_read.
// QKV (BM=256,BN=256): 4 loads/group all waves -> W1=4.
// proj (BM=256,BN=160): P1 group = {Ah:2, Bh:1-2} -> W1=3 (R4 known-good).
template<int BM, int ND, int BN, int NWM, int NWN, int EPI, int W1>
__global__ __launch_bounds__(512, 2)
void gemm8p(const uint16_t* __restrict__ Ahp, const uint16_t* __restrict__ Alp,
            const uint16_t* __restrict__ Bth, const uint16_t* __restrict__ Btl,
            const float* __restrict__ bias, float* __restrict__ oF,
            uint16_t* __restrict__ oq, uint16_t* __restrict__ ok,
            uint16_t* __restrict__ ov)
{
    constexpr int MI  = BM / (NWM * 16);
    constexpr int NI  = BN / (NWN * 16);
    constexpr int ABYTES = BM * 64;
    constexpr int BBYTES = BN * 64;
    constexpr int NT = HID / 32;             // 40 K-tiles
    static_assert(NWM * NWN == 8, "8 waves");
    static_assert(BM % (NWM * 16) == 0 && BN % (NWN * 16) == 0, "tile split");

    __shared__ __align__(1024) uint16_t AsH[2][ABYTES / 2];
    __shared__ __align__(1024) uint16_t AsL[2][ABYTES / 2];
    __shared__ __align__(1024) uint16_t BsH[2][BBYTES / 2];
    __shared__ __align__(1024) uint16_t BsL[2][BBYTES / 2];

    const int tid  = threadIdx.x;
    const int w    = tid >> 6;
    const int lane = tid & 63;
    const int quad = lane >> 4;
    const int l16  = lane & 15;
    const int wm   = w / NWN;
    const int wn   = w % NWN;

    const int n0 = blockIdx.x * BN;
    const int m0 = blockIdx.y * BM;

    const size_t stg = (size_t)(lane >> 2) * (HID * 2)
                     + (size_t)(((lane & 3) ^ ((lane >> 3) & 3)) << 4);
    const char* gAh = (const char*)Ahp + (size_t)m0 * (HID * 2) + stg;
    const char* gAl = (const char*)Alp + (size_t)m0 * (HID * 2) + stg;
    const char* gBh = (const char*)Bth + (size_t)n0 * (HID * 2) + stg;
    const char* gBl = (const char*)Btl + (size_t)n0 * (HID * 2) + stg;

    const int swz  = (quad ^ ((l16 >> 1) & 3)) << 4;
    const int aoff = (wm * (MI * 16) + l16) * 64 + swz;
    const int boff = (wn * (NI * 16) + l16) * 64 + swz;

    f32x4 acc[MI][NI];
    #pragma unroll
    for (int mi = 0; mi < MI; ++mi)
        #pragma unroll
        for (int ni = 0; ni < NI; ++ni) acc[mi][ni] = (f32x4){0.f, 0.f, 0.f, 0.f};

    // prologue: stage kt=0 in stream order [Ah, Bh, Bl, Al]
    stage_tile(gAh, (char*)AsH[0], w, 0, ABYTES);
    stage_tile(gBh, (char*)BsH[0], w, 0, BBYTES);
    stage_tile(gBl, (char*)BsL[0], w, 0, BBYTES);
    stage_tile(gAl, (char*)AsL[0], w, 0, ABYTES);
    SB(); vmwait<W1>(); BAR(); SB();

    for (int kt = 0; kt < NT - 1; ++kt) {
        const int s = kt & 1, t = s ^ 1;
        bf16x8 ah[MI], bh[NI];

        // ---- P1: hh ----
        #pragma unroll
        for (int mi = 0; mi < MI; ++mi)
            ah[mi] = *(const bf16x8*)((const char*)AsH[s] + aoff + mi * 1024);
        #pragma unroll
        for (int ni = 0; ni < NI; ++ni)
            bh[ni] = *(const bf16x8*)((const char*)BsH[s] + boff + ni * 1024);
        stage_tile(gAh, (char*)AsH[t], w, kt + 1, ABYTES);
        stage_tile(gBh, (char*)BsH[t], w, kt + 1, BBYTES);
        SB(); vmwait<W1>(); BAR(); SB();
        __builtin_amdgcn_s_setprio(1);
        #pragma unroll
        for (int mi = 0; mi < MI; ++mi)
            #pragma unroll
            for (int ni = 0; ni < NI; ++ni)
                acc[mi][ni] = MFMA16(ah[mi], bh[ni], acc[mi][ni]);
        __builtin_amdgcn_s_setprio(0);

        // ---- P2: hl (ah live) ----
        bf16x8 bl[NI];
        #pragma unroll
        for (int ni = 0; ni < NI; ++ni)
            bl[ni] = *(const bf16x8*)((const char*)BsL[s] + boff + ni * 1024);
        stage_tile(gBl, (char*)BsL[t], w, kt + 1, BBYTES);
        stage_tile(gAl, (char*)AsL[t], w, kt + 1, ABYTES);
        SB(); BAR(); SB();
        __builtin_amdgcn_s_setprio(1);
        #pragma unroll
        for (int mi = 0; mi < MI; ++mi)
            #pragma unroll
            for (int ni = 0; ni < NI; ++ni)
                acc[mi][ni] = MFMA16(ah[mi], bl[ni], acc[mi][ni]);
        __builtin_amdgcn_s_setprio(0);

        // ---- P3: lh (bh live) ----
        bf16x8 al[MI];
        #pragma unroll
        for (int mi = 0; mi < MI; ++mi)
            al[mi] = *(const bf16x8*)((const char*)AsL[s] + aoff + mi * 1024);
        SB(); vmwait<W1>(); BAR(); SB();
        __builtin_amdgcn_s_setprio(1);
        #pragma unroll
        for (int mi = 0; mi < MI; ++mi)
            #pragma unroll
            for (int ni = 0; ni < NI; ++ni)
                acc[mi][ni] = MFMA16(al[mi], bh[ni], acc[mi][ni]);
        __builtin_amdgcn_s_setprio(0);
    }

    // ---- peeled last K-tile ----
    {
        const int s = (NT - 1) & 1;
        bf16x8 ah[MI], bh[NI];
        #pragma unroll
        for (int mi = 0; mi < MI; ++mi)
            ah[mi] = *(const bf16x8*)((const char*)AsH[s] + aoff + mi * 1024);
        #pragma unroll
        for (int ni = 0; ni < NI; ++ni)
            bh[ni] = *(const bf16x8*)((const char*)BsH[s] + boff + ni * 1024);
        SB(); vmwait<0>(); BAR(); SB();
        __builtin_amdgcn_s_setprio(1);
        #pragma unroll
        for (int mi = 0; mi < MI; ++mi)
            #pragma unroll
            for (int ni = 0; ni < NI; ++ni)
                acc[mi][ni] = MFMA16(ah[mi], bh[ni], acc[mi][ni]);
        __builtin_amdgcn_s_setprio(0);

        bf16x8 bl[NI];
        #pragma unroll
        for (int ni = 0; ni < NI; ++ni)
            bl[ni] = *(const bf16x8*)((const char*)BsL[s] + boff + ni * 1024);
        #pragma unroll
        for (int mi = 0; mi < MI; ++mi)
            #pragma unroll
            for (int ni = 0; ni < NI; ++ni)
                acc[mi][ni] = MFMA16(ah[mi], bl[ni], acc[mi][ni]);

        bf16x8 al[MI];
        #pragma unroll
        for (int mi = 0; mi < MI; ++mi)
            al[mi] = *(const bf16x8*)((const char*)AsL[s] + aoff + mi * 1024);
        #pragma unroll
        for (int mi = 0; mi < MI; ++mi)
            #pragma unroll
            for (int ni = 0; ni < NI; ++ni)
                acc[mi][ni] = MFMA16(al[mi], bh[ni], acc[mi][ni]);
    }

    // ---- epilogue ----
    #pragma unroll
    for (int ni = 0; ni < NI; ++ni) {
        const int n = n0 + wn * (NI * 16) + ni * 16 + l16;
        const float bv = bias[n];
        if constexpr (EPI) {
            const int tq  = n / HID;
            const int rem = n - tq * HID;
            const int h   = rem / HD;
            const int d   = rem - h * HD;
            #pragma unroll
            for (int mi = 0; mi < MI; ++mi) {
                const int mb = m0 + wm * (MI * 16) + mi * 16 + quad * 4;
                if (tq == 2) {
                    ushort4 pv;
                    pv.x = f2bf(acc[mi][ni][0] + bv);
                    pv.y = f2bf(acc[mi][ni][1] + bv);
                    pv.z = f2bf(acc[mi][ni][2] + bv);
                    pv.w = f2bf(acc[mi][ni][3] + bv);
                    *(ushort4*)&ov[((size_t)h * HD + d) * S_LEN + mb] = pv;
                } else {
                    uint16_t* dst = (tq == 0) ? oq : ok;
                    #pragma unroll
                    for (int r = 0; r < 4; ++r)
                        dst[((size_t)h * S_LEN + (mb + r)) * HD + d] =
                            f2bf(acc[mi][ni][r] + bv);
                }
            }
        } else {
            #pragma unroll
            for (int mi = 0; mi < MI; ++mi) {
                const int mb = m0 + wm * (MI * 16) + mi * 16 + quad * 4;
                #pragma unroll
                for (int r = 0; r < 4; ++r)
                    oF[(size_t)(mb + r) * ND + n] = acc[mi][ni][r] + bv;
            }
        }
    }
}

// ---------------- rope: vectorized, one thread per (h,s) row of 80 ----------------
__global__ __launch_bounds__(256)
void rope_kernel(uint16_t* __restrict__ qb, uint16_t* __restrict__ kb,
                 const float* __restrict__ cosb, const float* __restrict__ sinb)
{
    const int t = blockIdx.x * 256 + threadIdx.x;    // h*S_LEN + s
    const int s = t & (S_LEN - 1);
    uint16_t* qr = qb + (size_t)t * HD;
    uint16_t* kr = kb + (size_t)t * HD;
    const float* cr = cosb + (size_t)s * HD;
    const float* sr = sinb + (size_t)s * HD;
    #pragma unroll
    for (int ch = 0; ch < 5; ++ch) {
        const int d = ch * 8;
        u16x8 q1 = *(const u16x8*)(qr + d);
        u16x8 q2 = *(const u16x8*)(qr + d + 40);
        u16x8 k1 = *(const u16x8*)(kr + d);
        u16x8 k2 = *(const u16x8*)(kr + d + 40);
        float c1[8], c2[8], s1[8], s2[8];
        *(float4*)&c1[0] = *(const float4*)(cr + d);
        *(float4*)&c1[4] = *(const float4*)(cr + d + 4);
        *(float4*)&c2[0] = *(const float4*)(cr + d + 40);
        *(float4*)&c2[4] = *(const float4*)(cr + d + 44);
        *(float4*)&s1[0] = *(const float4*)(sr + d);
        *(float4*)&s1[4] = *(const float4*)(sr + d + 4);
        *(float4*)&s2[0] = *(const float4*)(sr + d + 40);
        *(float4*)&s2[4] = *(const float4*)(sr + d + 44);
        u16x8 o1, o2, p1, p2;
        #pragma unroll
        for (int j = 0; j < 8; ++j) {
            float q1f = bf2f((uint16_t)q1[j]), q2f = bf2f((uint16_t)q2[j]);
            o1[j] = f2bf(q1f * c1[j] - q2f * s1[j]);
            o2[j] = f2bf(q2f * c2[j] + q1f * s2[j]);
            float k1f = bf2f((uint16_t)k1[j]), k2f = bf2f((uint16_t)k2[j]);
            p1[j] = f2bf(k1f * c1[j] - k2f * s1[j]);
            p2[j] = f2bf(k2f * c2[j] + k1f * s2[j]);
        }
        *(u16x8*)(qr + d)      = o1;
        *(u16x8*)(qr + d + 40) = o2;
        *(u16x8*)(kr + d)      = p1;
        *(u16x8*)(kr + d + 40) = p2;
    }
}

// ---------------- MFMA flash attention, BQ=256, 8 waves, single-barrier loop ----------
// K AND V double-buffered -> ONE __syncthreads per K-tile (was 2). LDS = 40960
// (Q/psw) + 2*10240 (K) + 2*10240 (V) = 81920 B; 2 blocks/CU = exactly the
// 163840 B pool. Per K-tile: {sync: K(kt),V(kt) landed + prev reads done;
// prefetch K(kt+1),V(kt+1) into bufs t; QK from ksm[s]; softmax -> psw
// (per-wave region, same-wave read in PV); PV from vsm[s]}. All read/write
// buffer pairs disjoint; barrier keeps waves within one iteration.
#define BQ 256
#define BK 64

__device__ __forceinline__ void kstage(const char* kg, char* dst, int w, int lane)
{
    int p = w * 1024 + lane * 16;
    {   // regA: phys (row, sl) holds global d-slot sl^(row&7)
        int row = p >> 7;
        int sl  = (p >> 4) & 7;
        glds16(kg + row * 160 + ((sl ^ (row & 7)) << 4), dst + p);
    }
    int p2 = p + 8192;
    if (p2 < 10240) {   // regB: waves 0,1; identity mapping, d-slots 8,9
        int q   = p2 - 8192;
        int row = q >> 5;
        int sl  = (q >> 4) & 1;
        glds16(kg + row * 160 + 128 + (sl << 4), dst + p2);
    }
}

__device__ __forceinline__ void vstage(const char* vg, char* dst, size_t vrow_stride,
                                       int w, int lane)
{
    for (int off = w * 1024; off < HD * BK * 2; off += 8192) {
        int o   = off + lane * 16;
        int row = o >> 7;
        int col = o & 127;
        glds16(vg + (size_t)row * vrow_stride + (col ^ ((row & 7) << 4)), dst + off);
    }
}

__global__ __launch_bounds__(512, 4)
void attn_kernel(const uint16_t* __restrict__ qb, const uint16_t* __restrict__ kb,
                 const uint16_t* __restrict__ vt,
                 uint16_t* __restrict__ abh, uint16_t* __restrict__ abl)
{
    __shared__ __align__(16) uint16_t smemA[BQ * HD];     // 40960 B: Q staging, then psw
    __shared__ __align__(16) uint16_t ksm[2][BK * HD];    // K tiles dbuf (regA+regB)
    __shared__ __align__(16) uint16_t vsm[2][HD * BK];    // V tiles dbuf [d][k], swizzled

    const int tid  = threadIdx.x;
    const int w    = tid >> 6;
    const int lane = tid & 63;
    const int quad = lane >> 4;
    const int l16  = lane & 15;

    const int qt = blockIdx.x;
    const int h  = blockIdx.y;
    const int c  = blockIdx.z;
    const int q0 = c * LCH + qt * BQ;

    uint16_t (*psw)[68] = (uint16_t(*)[68])smemA + w * 32;

    {
        const char* qg = (const char*)(qb + ((size_t)h * S_LEN + q0) * HD);
        for (int off = w * 1024; off < BQ * HD * 2; off += 8192)
            glds16(qg + off + lane * 16, (char*)smemA + off);
    }
    __syncthreads();   // Q staged

    bf16x8 qfr[2][3];
    #pragma unroll
    for (int mi = 0; mi < 2; ++mi) {
        const int row = w * 32 + mi * 16 + l16;
        qfr[mi][0] = *(const bf16x8*)&smemA[row * HD + quad * 8];
        qfr[mi][1] = *(const bf16x8*)&smemA[row * HD + 32 + quad * 8];
        bf16x8 z = {0, 0, 0, 0, 0, 0, 0, 0};
        qfr[mi][2] = (quad < 2) ? *(const bf16x8*)&smemA[row * HD + 64 + quad * 8] : z;
    }

    bf16x8 vf5;
    {
        short o = (l16 == 0) ? (short)0x3F80 : (short)0;
        vf5 = (bf16x8){o, o, o, o, o, o, o, o};
    }

    f32x4 Oacc[2][6];
    #pragma unroll
    for (int mi = 0; mi < 2; ++mi)
        #pragma unroll
        for (int d = 0; d < 6; d++) Oacc[mi][d] = (f32x4){0.f, 0.f, 0.f, 0.f};

    const float C2 = 0.11180339887498949f * 1.4426950408889634f;  // 1/sqrt(80)*log2e
    const char* kg0 = (const char*)(kb + ((size_t)h * S_LEN + c * LCH) * HD);
    const size_t vrow_stride = (size_t)S_LEN * 2;
    const char* vg0 = (const char*)vt + (size_t)h * HD * S_LEN * 2 + (size_t)(c * LCH) * 2;

    // prefetch K(0), V(0) into buffers 0
    kstage(kg0, (char*)&ksm[0][0], w, lane);
    vstage(vg0, (char*)&vsm[0][0], vrow_stride, w, lane);

    for (int kt = 0; kt < LCH / BK; ++kt) {
        const int s = kt & 1;
        __syncthreads();   // K(kt),V(kt) landed; prev-iter reads done; psw safe

        if (kt + 1 < LCH / BK) {
            kstage(kg0 + (size_t)(kt + 1) * BK * HD * 2,
                   (char*)&ksm[s ^ 1][0], w, lane);
            vstage(vg0 + (size_t)((kt + 1) * BK) * 2,
                   (char*)&vsm[s ^ 1][0], vrow_stride, w, lane);
        }

        // ---- S^T = K Q^T (swapped): rows=k, cols=q; softmax+pack per ns ----
        const char* ksb = (const char*)&ksm[s][0];
        #pragma unroll
        for (int ns = 0; ns < 4; ++ns) {
            const int kr = ns * 16 + l16;
            const int sw = (kr & 7) << 4;
            bf16x8 kf0 = *(const bf16x8*)(ksb + kr * 128 + ((quad * 16) ^ sw));
            bf16x8 kf1 = *(const bf16x8*)(ksb + kr * 128 + ((64 + quad * 16) ^ sw));
            bf16x8 z = {0, 0, 0, 0, 0, 0, 0, 0};
            bf16x8 kf2 = (quad < 2)
                ? *(const bf16x8*)(ksb + 8192 + kr * 32 + quad * 16) : z;
            #pragma unroll
            for (int mi = 0; mi < 2; ++mi) {
                f32x4 sv = (f32x4){0.f, 0.f, 0.f, 0.f};
                sv = MFMA16(kf0, qfr[mi][0], sv);
                sv = MFMA16(kf1, qfr[mi][1], sv);
                sv = MFMA16(kf2, qfr[mi][2], sv);
                float e0 = exp2f(sv[0] * C2);
                float e1 = exp2f(sv[1] * C2);
                float e2 = exp2f(sv[2] * C2);
                float e3 = exp2f(sv[3] * C2);
                *(uint2*)&psw[mi * 16 + l16][ns * 16 + quad * 4] =
                    (uint2){pk2(e0, e1), pk2(e2, e3)};
            }
        }

        // ---- O += P V (V(kt) already resident; psw same-wave) ----
        const char* vsb = (const char*)&vsm[s][0];
        #pragma unroll
        for (int kc = 0; kc < 2; ++kc) {
            bf16x8 pf[2];
            #pragma unroll
            for (int mi = 0; mi < 2; ++mi) {
                const uint16_t* pp = &psw[mi * 16 + l16][kc * 32 + quad * 8];
                ((uint2*)&pf[mi])[0] = *(const uint2*)(pp);
                ((uint2*)&pf[mi])[1] = *(const uint2*)(pp + 4);
            }
            #pragma unroll
            for (int ds = 0; ds < 5; ++ds) {
                const int vr = ds * 16 + l16;
                bf16x8 vf = *(const bf16x8*)(vsb + vr * 128 +
                    ((kc * 64 + quad * 16) ^ ((vr & 7) << 4)));
                #pragma unroll
                for (int mi = 0; mi < 2; ++mi)
                    Oacc[mi][ds] = MFMA16(pf[mi], vf, Oacc[mi][ds]);
            }
            #pragma unroll
            for (int mi = 0; mi < 2; ++mi)
                Oacc[mi][5] = MFMA16(pf[mi], vf5, Oacc[mi][5]);
        }
    }

    // epilogue: l = ones-column (col 0 of slab 5); O/l -> split hi/lo bf16 ab
    #pragma unroll
    for (int mi = 0; mi < 2; ++mi)
        #pragma unroll
        for (int r = 0; r < 4; ++r) {
            float l = __shfl(Oacc[mi][5][r], lane & 48);
            float inv = 1.f / l;
            const int srow = q0 + w * 32 + mi * 16 + quad * 4 + r;
            const size_t rowbase = (size_t)srow * HID + h * HD;
            #pragma unroll
            for (int ds = 0; ds < 5; ++ds) {
                float f = Oacc[mi][ds][r] * inv;
                uint16_t hi = f2bf(f);
                abh[rowbase + ds * 16 + l16] = hi;
                abl[rowbase + ds * 16 + l16] = f2bf(f - bf2f(hi));
            }
        }
}

extern "C" void kernel_launch(void* const* d_in, const int* in_sizes, int n_in,
                              void* d_out, int out_size, void* d_ws, size_t ws_size,
                              hipStream_t stream)
{
    const float* x     = (const float*)d_in[0];
    const float* cosb  = (const float*)d_in[1];
    const float* sinb  = (const float*)d_in[2];
    const float* Wqkv  = (const float*)d_in[3];
    const float* bqkv  = (const float*)d_in[4];
    const float* Wproj = (const float*)d_in[5];
    const float* bproj = (const float*)d_in[6];
    float* out = (float*)d_out;

    const size_t E = (size_t)NH * S_LEN * HD;   // 10,485,760 (= S*HID)
    uint16_t* qb  = (uint16_t*)d_ws;            // [h][s][80]
    uint16_t* kb  = qb + E;                     // [h][s][80]
    uint16_t* vt  = kb + E;                     // [h][80][s]
    uint16_t* xh  = vt + E;                     // x_hi [s][1280]; later ab_hi
    uint16_t* xl  = xh + E;                     // x_lo;           later ab_lo
    uint16_t* wth = xl + E;                     // W^T hi
    uint16_t* wtl = wth + (size_t)3 * HID * HID;

    xsplit_kernel<<<(S_LEN * HID) / (256 * 4), 256, 0, stream>>>(x, xh, xl);
    wsplit_kernel<3 * HID><<<dim3(3 * HID / 32, HID / 32), 256, 0, stream>>>(Wqkv, wth, wtl);
    // QKV: BM=256, BN=256, waves 2x4, schedule B, W1=4  (known-good)
    gemm8p<256, 3 * HID, 256, 2, 4, 1, 4>
        <<<dim3(3 * HID / 256, S_LEN / 256), 512, 0, stream>>>(
        xh, xl, wth, wtl, bqkv, nullptr, qb, kb, vt);
    rope_kernel<<<(NH * S_LEN) / 256, 256, 0, stream>>>(qb, kb, cosb, sinb);
    attn_kernel<<<dim3(LCH / BQ, NH, NCH), 512, 0, stream>>>(qb, kb, vt, xh, xl);
    wsplit_kernel<HID><<<dim3(HID / 32, HID / 32), 256, 0, stream>>>(Wproj, wth, wtl);
    // proj: BM=256, BN=160 -> 256 blocks, waves 4x2, schedule B, W1=3 (R4 config)
    gemm8p<256, HID, 160, 4, 2, 0, 3>
        <<<dim3(HID / 160, S_LEN / 256), 512, 0, stream>>>(
        xh, xl, wth, wtl, bproj, out, nullptr, nullptr, nullptr);
}

// Round 8
// 493.200 us; speedup vs baseline: 1.1463x; 1.0637x over previous
//
#include <hip/hip_runtime.h>
#include <math.h>
#include <stdint.h>

#define S_LEN 8192
#define HID   1280
#define NH    16
#define HD    80
#define LCH   1024
#define NCH   8

typedef __attribute__((ext_vector_type(8))) short bf16x8;
typedef __attribute__((ext_vector_type(4))) float f32x4;

__device__ __forceinline__ uint16_t f2bf(float f) {
    union { float f; uint32_t u; } v; v.f = f;
    uint32_t r = v.u + 0x7FFF + ((v.u >> 16) & 1);   // RNE
    return (uint16_t)(r >> 16);
}
__device__ __forceinline__ float bf2f(uint16_t h) {
    union { uint32_t u; float f; } v; v.u = ((uint32_t)h) << 16;
    return v.f;
}
__device__ __forceinline__ uint32_t pk2(float a, float b) {   // trunc-bf16 pair pack
    union { float f; uint32_t u; } x, y; x.f = a; y.f = b;
    return (x.u >> 16) | (y.u & 0xFFFF0000u);
}

__device__ __forceinline__ void glds16(const void* g, void* l) {
    __builtin_amdgcn_global_load_lds(
        (const __attribute__((address_space(1))) uint32_t*)g,
        (__attribute__((address_space(3))) uint32_t*)l,
        16, 0, 0);
}

#define MFMA16(a, b, c) __builtin_amdgcn_mfma_f32_16x16x32_bf16(a, b, c, 0, 0, 0)
#define SB()  __builtin_amdgcn_sched_barrier(0)
#define BAR() __builtin_amdgcn_s_barrier()

template<int N> __device__ __forceinline__ void vmwait() {
    if constexpr (N == 0) asm volatile("s_waitcnt vmcnt(0)" ::: "memory");
    else if constexpr (N == 2) asm volatile("s_waitcnt vmcnt(2)" ::: "memory");
    else if constexpr (N == 3) asm volatile("s_waitcnt vmcnt(3)" ::: "memory");
    else if constexpr (N == 4) asm volatile("s_waitcnt vmcnt(4)" ::: "memory");
}

// stage one [rows x 32] bf16 K-tile (nbytes = rows*64) into LDS, linear dest,
// global source pre-swizzled per lane so the ds_read-side XOR swizzle matches.
// chunk advance: 1024 B LDS <-> 16 rows * 2560 B global = off*40.
__device__ __forceinline__ void stage_tile(const char* gsrc, char* dst, int w,
                                           int kt, int nbytes)
{
    const char* sp = gsrc + (size_t)kt * 64;
    int off = w * 1024;
    glds16(sp + (size_t)off * 40, dst + off);
    off += 8192;
    if (off < nbytes) glds16(sp + (size_t)off * 40, dst + off);
}

// ---------------- prepass: split x fp32 -> hi/lo bf16 (same layout) ----------------
__global__ __launch_bounds__(256)
void xsplit_kernel(const float* __restrict__ x, uint16_t* __restrict__ xh,
                   uint16_t* __restrict__ xl)
{
    int idx = (blockIdx.x * 256 + threadIdx.x) * 4;
    float4 v = *(const float4*)(x + idx);
    ushort4 hi, lo;
    hi.x = f2bf(v.x); lo.x = f2bf(v.x - bf2f(hi.x));
    hi.y = f2bf(v.y); lo.y = f2bf(v.y - bf2f(hi.y));
    hi.z = f2bf(v.z); lo.z = f2bf(v.z - bf2f(hi.z));
    hi.w = f2bf(v.w); lo.w = f2bf(v.w - bf2f(hi.w));
    *(ushort4*)(xh + idx) = hi;
    *(ushort4*)(xl + idx) = lo;
}

// ---------------- prepass: W [1280][ND] fp32 -> W^T [ND][1280] hi/lo bf16 ----------------
template<int ND>
__global__ __launch_bounds__(256)
void wsplit_kernel(const float* __restrict__ W, uint16_t* __restrict__ Wth,
                   uint16_t* __restrict__ Wtl)
{
    __shared__ float t[32][33];
    const int tid = threadIdx.x;
    const int n0 = blockIdx.x * 32;
    const int k0 = blockIdx.y * 32;
    for (int i = tid; i < 1024; i += 256) {
        int r = i >> 5, c = i & 31;
        t[r][c] = W[(size_t)(k0 + r) * ND + n0 + c];
    }
    __syncthreads();
    for (int i = tid; i < 1024; i += 256) {
        int r = i >> 5, c = i & 31;          // r: n offset, c: k offset
        float f = t[c][r];
        uint16_t hi = f2bf(f);
        size_t o = (size_t)(n0 + r) * HID + k0 + c;
        Wth[o] = hi;
        Wtl[o] = f2bf(f - bf2f(hi));
    }
}

// ---------------- split-bf16 MFMA GEMM, 3-phase counted-vmcnt pipeline (schedule B) ----
// P1 {read ah,bh | stage Ah,Bh(t+1) | vmcnt(W1) | bar | MFMA hh}
// P2 {read bl    | stage Bl,Al(t+1) |            bar | MFMA hl}
// P3 {read al    |                  | vmcnt(W1) | bar | MFMA lh}
// Every buffer's landing is enforced one full phase before its first ds_read.
// QKV (BM=256,BN=256): 4 loads/group all waves -> W1=4.
// proj (BM=256,BN=160): P1 group = {Ah:2, Bh:1-2} -> W1=3 (R4 known-good).
template<int BM, int ND, int BN, int NWM, int NWN, int EPI, int W1>
__global__ __launch_bounds__(512, 2)
void gemm8p(const uint16_t* __restrict__ Ahp, const uint16_t* __restrict__ Alp,
            const uint16_t* __restrict__ Bth, const uint16_t* __restrict__ Btl,
            const float* __restrict__ bias, float* __restrict__ oF,
            uint16_t* __restrict__ oq, uint16_t* __restrict__ ok,
            uint16_t* __restrict__ ov)
{
    constexpr int MI  = BM / (NWM * 16);
    constexpr int NI  = BN / (NWN * 16);
    constexpr int ABYTES = BM * 64;
    constexpr int BBYTES = BN * 64;
    constexpr int NT = HID / 32;             // 40 K-tiles
    static_assert(NWM * NWN == 8, "8 waves");
    static_assert(BM % (NWM * 16) == 0 && BN % (NWN * 16) == 0, "tile split");

    __shared__ __align__(1024) uint16_t AsH[2][ABYTES / 2];
    __shared__ __align__(1024) uint16_t AsL[2][ABYTES / 2];
    __shared__ __align__(1024) uint16_t BsH[2][BBYTES / 2];
    __shared__ __align__(1024) uint16_t BsL[2][BBYTES / 2];

    const int tid  = threadIdx.x;
    const int w    = tid >> 6;
    const int lane = tid & 63;
    const int quad = lane >> 4;
    const int l16  = lane & 15;
    const int wm   = w / NWN;
    const int wn   = w % NWN;

    const int n0 = blockIdx.x * BN;
    const int m0 = blockIdx.y * BM;

    const size_t stg = (size_t)(lane >> 2) * (HID * 2)
                     + (size_t)(((lane & 3) ^ ((lane >> 3) & 3)) << 4);
    const char* gAh = (const char*)Ahp + (size_t)m0 * (HID * 2) + stg;
    const char* gAl = (const char*)Alp + (size_t)m0 * (HID * 2) + stg;
    const char* gBh = (const char*)Bth + (size_t)n0 * (HID * 2) + stg;
    const char* gBl = (const char*)Btl + (size_t)n0 * (HID * 2) + stg;

    const int swz  = (quad ^ ((l16 >> 1) & 3)) << 4;
    const int aoff = (wm * (MI * 16) + l16) * 64 + swz;
    const int boff = (wn * (NI * 16) + l16) * 64 + swz;

    f32x4 acc[MI][NI];
    #pragma unroll
    for (int mi = 0; mi < MI; ++mi)
        #pragma unroll
        for (int ni = 0; ni < NI; ++ni) acc[mi][ni] = (f32x4){0.f, 0.f, 0.f, 0.f};

    // prologue: stage kt=0 in stream order [Ah, Bh, Bl, Al]
    stage_tile(gAh, (char*)AsH[0], w, 0, ABYTES);
    stage_tile(gBh, (char*)BsH[0], w, 0, BBYTES);
    stage_tile(gBl, (char*)BsL[0], w, 0, BBYTES);
    stage_tile(gAl, (char*)AsL[0], w, 0, ABYTES);
    SB(); vmwait<W1>(); BAR(); SB();

    for (int kt = 0; kt < NT - 1; ++kt) {
        const int s = kt & 1, t = s ^ 1;
        bf16x8 ah[MI], bh[NI];

        // ---- P1: hh ----
        #pragma unroll
        for (int mi = 0; mi < MI; ++mi)
            ah[mi] = *(const bf16x8*)((const char*)AsH[s] + aoff + mi * 1024);
        #pragma unroll
        for (int ni = 0; ni < NI; ++ni)
            bh[ni] = *(const bf16x8*)((const char*)BsH[s] + boff + ni * 1024);
        stage_tile(gAh, (char*)AsH[t], w, kt + 1, ABYTES);
        stage_tile(gBh, (char*)BsH[t], w, kt + 1, BBYTES);
        SB(); vmwait<W1>(); BAR(); SB();
        __builtin_amdgcn_s_setprio(1);
        #pragma unroll
        for (int mi = 0; mi < MI; ++mi)
            #pragma unroll
            for (int ni = 0; ni < NI; ++ni)
                acc[mi][ni] = MFMA16(ah[mi], bh[ni], acc[mi][ni]);
        __builtin_amdgcn_s_setprio(0);

        // ---- P2: hl (ah live) ----
        bf16x8 bl[NI];
        #pragma unroll
        for (int ni = 0; ni < NI; ++ni)
            bl[ni] = *(const bf16x8*)((const char*)BsL[s] + boff + ni * 1024);
        stage_tile(gBl, (char*)BsL[t], w, kt + 1, BBYTES);
        stage_tile(gAl, (char*)AsL[t], w, kt + 1, ABYTES);
        SB(); BAR(); SB();
        __builtin_amdgcn_s_setprio(1);
        #pragma unroll
        for (int mi = 0; mi < MI; ++mi)
            #pragma unroll
            for (int ni = 0; ni < NI; ++ni)
                acc[mi][ni] = MFMA16(ah[mi], bl[ni], acc[mi][ni]);
        __builtin_amdgcn_s_setprio(0);

        // ---- P3: lh (bh live) ----
        bf16x8 al[MI];
        #pragma unroll
        for (int mi = 0; mi < MI; ++mi)
            al[mi] = *(const bf16x8*)((const char*)AsL[s] + aoff + mi * 1024);
        SB(); vmwait<W1>(); BAR(); SB();
        __builtin_amdgcn_s_setprio(1);
        #pragma unroll
        for (int mi = 0; mi < MI; ++mi)
            #pragma unroll
            for (int ni = 0; ni < NI; ++ni)
                acc[mi][ni] = MFMA16(al[mi], bh[ni], acc[mi][ni]);
        __builtin_amdgcn_s_setprio(0);
    }

    // ---- peeled last K-tile ----
    {
        const int s = (NT - 1) & 1;
        bf16x8 ah[MI], bh[NI];
        #pragma unroll
        for (int mi = 0; mi < MI; ++mi)
            ah[mi] = *(const bf16x8*)((const char*)AsH[s] + aoff + mi * 1024);
        #pragma unroll
        for (int ni = 0; ni < NI; ++ni)
            bh[ni] = *(const bf16x8*)((const char*)BsH[s] + boff + ni * 1024);
        SB(); vmwait<0>(); BAR(); SB();
        __builtin_amdgcn_s_setprio(1);
        #pragma unroll
        for (int mi = 0; mi < MI; ++mi)
            #pragma unroll
            for (int ni = 0; ni < NI; ++ni)
                acc[mi][ni] = MFMA16(ah[mi], bh[ni], acc[mi][ni]);
        __builtin_amdgcn_s_setprio(0);

        bf16x8 bl[NI];
        #pragma unroll
        for (int ni = 0; ni < NI; ++ni)
            bl[ni] = *(const bf16x8*)((const char*)BsL[s] + boff + ni * 1024);
        #pragma unroll
        for (int mi = 0; mi < MI; ++mi)
            #pragma unroll
            for (int ni = 0; ni < NI; ++ni)
                acc[mi][ni] = MFMA16(ah[mi], bl[ni], acc[mi][ni]);

        bf16x8 al[MI];
        #pragma unroll
        for (int mi = 0; mi < MI; ++mi)
            al[mi] = *(const bf16x8*)((const char*)AsL[s] + aoff + mi * 1024);
        #pragma unroll
        for (int mi = 0; mi < MI; ++mi)
            #pragma unroll
            for (int ni = 0; ni < NI; ++ni)
                acc[mi][ni] = MFMA16(al[mi], bh[ni], acc[mi][ni]);
    }

    // ---- epilogue ----
    #pragma unroll
    for (int ni = 0; ni < NI; ++ni) {
        const int n = n0 + wn * (NI * 16) + ni * 16 + l16;
        const float bv = bias[n];
        if constexpr (EPI) {
            const int tq  = n / HID;
            const int rem = n - tq * HID;
            const int h   = rem / HD;
            const int d   = rem - h * HD;
            #pragma unroll
            for (int mi = 0; mi < MI; ++mi) {
                const int mb = m0 + wm * (MI * 16) + mi * 16 + quad * 4;
                if (tq == 2) {
                    ushort4 pv;
                    pv.x = f2bf(acc[mi][ni][0] + bv);
                    pv.y = f2bf(acc[mi][ni][1] + bv);
                    pv.z = f2bf(acc[mi][ni][2] + bv);
                    pv.w = f2bf(acc[mi][ni][3] + bv);
                    *(ushort4*)&ov[((size_t)h * HD + d) * S_LEN + mb] = pv;
                } else {
                    uint16_t* dst = (tq == 0) ? oq : ok;
                    #pragma unroll
                    for (int r = 0; r < 4; ++r)
                        dst[((size_t)h * S_LEN + (mb + r)) * HD + d] =
                            f2bf(acc[mi][ni][r] + bv);
                }
            }
        } else {
            #pragma unroll
            for (int mi = 0; mi < MI; ++mi) {
                const int mb = m0 + wm * (MI * 16) + mi * 16 + quad * 4;
                #pragma unroll
                for (int r = 0; r < 4; ++r)
                    oF[(size_t)(mb + r) * ND + n] = acc[mi][ni][r] + bv;
            }
        }
    }
}

// ---------------- rope: in-place on bf16 q and k, layout [h][s][80] (R4 scalar) --------
__global__ __launch_bounds__(256)
void rope_kernel(uint16_t* __restrict__ qb, uint16_t* __restrict__ kb,
                 const float* __restrict__ cosb, const float* __restrict__ sinb)
{
    int idx = blockIdx.x * 256 + threadIdx.x;
    int d = idx % 40;
    int t = idx / 40;
    int s = t % S_LEN;
    int h = t / S_LEN;
    size_t base = ((size_t)h * S_LEN + s) * HD;
    float c1 = cosb[s * HD + d],      s1 = sinb[s * HD + d];
    float c2 = cosb[s * HD + d + 40], s2 = sinb[s * HD + d + 40];
    float q1 = bf2f(qb[base + d]), q2 = bf2f(qb[base + d + 40]);
    qb[base + d]      = f2bf(q1 * c1 - q2 * s1);
    qb[base + d + 40] = f2bf(q2 * c2 + q1 * s2);
    float k1 = bf2f(kb[base + d]), k2 = bf2f(kb[base + d + 40]);
    kb[base + d]      = f2bf(k1 * c1 - k2 * s1);
    kb[base + d + 40] = f2bf(k2 * c2 + k1 * s2);
}

// ---------------- MFMA flash attention, BQ=256, 8 waves, single-barrier loop ----------
// K AND V double-buffered -> ONE __syncthreads per K-tile. LDS = 40960 (Q/psw)
// + 2*10240 (K) + 2*10240 (V) = 81920 B; 2 blocks/CU. Per K-tile: {sync;
// prefetch K(kt+1),V(kt+1) into bufs t; QK from ksm[s]; softmax -> psw; PV from
// vsm[s]}. All read/write buffer pairs disjoint; barrier keeps waves in step.
#define BQ 256
#define BK 64

__device__ __forceinline__ void kstage(const char* kg, char* dst, int w, int lane)
{
    int p = w * 1024 + lane * 16;
    {   // regA: phys (row, sl) holds global d-slot sl^(row&7)
        int row = p >> 7;
        int sl  = (p >> 4) & 7;
        glds16(kg + row * 160 + ((sl ^ (row & 7)) << 4), dst + p);
    }
    int p2 = p + 8192;
    if (p2 < 10240) {   // regB: waves 0,1; identity mapping, d-slots 8,9
        int q   = p2 - 8192;
        int row = q >> 5;
        int sl  = (q >> 4) & 1;
        glds16(kg + row * 160 + 128 + (sl << 4), dst + p2);
    }
}

__device__ __forceinline__ void vstage(const char* vg, char* dst, size_t vrow_stride,
                                       int w, int lane)
{
    for (int off = w * 1024; off < HD * BK * 2; off += 8192) {
        int o   = off + lane * 16;
        int row = o >> 7;
        int col = o & 127;
        glds16(vg + (size_t)row * vrow_stride + (col ^ ((row & 7) << 4)), dst + off);
    }
}

__global__ __launch_bounds__(512, 4)
void attn_kernel(const uint16_t* __restrict__ qb, const uint16_t* __restrict__ kb,
                 const uint16_t* __restrict__ vt,
                 uint16_t* __restrict__ abh, uint16_t* __restrict__ abl)
{
    __shared__ __align__(16) uint16_t smemA[BQ * HD];     // 40960 B: Q staging, then psw
    __shared__ __align__(16) uint16_t ksm[2][BK * HD];    // K tiles dbuf (regA+regB)
    __shared__ __align__(16) uint16_t vsm[2][HD * BK];    // V tiles dbuf [d][k], swizzled

    const int tid  = threadIdx.x;
    const int w    = tid >> 6;
    const int lane = tid & 63;
    const int quad = lane >> 4;
    const int l16  = lane & 15;

    const int qt = blockIdx.x;
    const int h  = blockIdx.y;
    const int c  = blockIdx.z;
    const int q0 = c * LCH + qt * BQ;

    uint16_t (*psw)[68] = (uint16_t(*)[68])smemA + w * 32;

    {
        const char* qg = (const char*)(qb + ((size_t)h * S_LEN + q0) * HD);
        for (int off = w * 1024; off < BQ * HD * 2; off += 8192)
            glds16(qg + off + lane * 16, (char*)smemA + off);
    }
    __syncthreads();   // Q staged

    bf16x8 qfr[2][3];
    #pragma unroll
    for (int mi = 0; mi < 2; ++mi) {
        const int row = w * 32 + mi * 16 + l16;
        qfr[mi][0] = *(const bf16x8*)&smemA[row * HD + quad * 8];
        qfr[mi][1] = *(const bf16x8*)&smemA[row * HD + 32 + quad * 8];
        bf16x8 z = {0, 0, 0, 0, 0, 0, 0, 0};
        qfr[mi][2] = (quad < 2) ? *(const bf16x8*)&smemA[row * HD + 64 + quad * 8] : z;
    }

    bf16x8 vf5;
    {
        short o = (l16 == 0) ? (short)0x3F80 : (short)0;
        vf5 = (bf16x8){o, o, o, o, o, o, o, o};
    }

    f32x4 Oacc[2][6];
    #pragma unroll
    for (int mi = 0; mi < 2; ++mi)
        #pragma unroll
        for (int d = 0; d < 6; d++) Oacc[mi][d] = (f32x4){0.f, 0.f, 0.f, 0.f};

    const float C2 = 0.11180339887498949f * 1.4426950408889634f;  // 1/sqrt(80)*log2e
    const char* kg0 = (const char*)(kb + ((size_t)h * S_LEN + c * LCH) * HD);
    const size_t vrow_stride = (size_t)S_LEN * 2;
    const char* vg0 = (const char*)vt + (size_t)h * HD * S_LEN * 2 + (size_t)(c * LCH) * 2;

    // prefetch K(0), V(0) into buffers 0
    kstage(kg0, (char*)&ksm[0][0], w, lane);
    vstage(vg0, (char*)&vsm[0][0], vrow_stride, w, lane);

    for (int kt = 0; kt < LCH / BK; ++kt) {
        const int s = kt & 1;
        __syncthreads();   // K(kt),V(kt) landed; prev-iter reads done; psw safe

        if (kt + 1 < LCH / BK) {
            kstage(kg0 + (size_t)(kt + 1) * BK * HD * 2,
                   (char*)&ksm[s ^ 1][0], w, lane);
            vstage(vg0 + (size_t)((kt + 1) * BK) * 2,
                   (char*)&vsm[s ^ 1][0], vrow_stride, w, lane);
        }

        // ---- S^T = K Q^T (swapped): rows=k, cols=q; softmax+pack per ns ----
        const char* ksb = (const char*)&ksm[s][0];
        #pragma unroll
        for (int ns = 0; ns < 4; ++ns) {
            const int kr = ns * 16 + l16;
            const int sw = (kr & 7) << 4;
            bf16x8 kf0 = *(const bf16x8*)(ksb + kr * 128 + ((quad * 16) ^ sw));
            bf16x8 kf1 = *(const bf16x8*)(ksb + kr * 128 + ((64 + quad * 16) ^ sw));
            bf16x8 z = {0, 0, 0, 0, 0, 0, 0, 0};
            bf16x8 kf2 = (quad < 2)
                ? *(const bf16x8*)(ksb + 8192 + kr * 32 + quad * 16) : z;
            #pragma unroll
            for (int mi = 0; mi < 2; ++mi) {
                f32x4 sv = (f32x4){0.f, 0.f, 0.f, 0.f};
                sv = MFMA16(kf0, qfr[mi][0], sv);
                sv = MFMA16(kf1, qfr[mi][1], sv);
                sv = MFMA16(kf2, qfr[mi][2], sv);
                float e0 = exp2f(sv[0] * C2);
                float e1 = exp2f(sv[1] * C2);
                float e2 = exp2f(sv[2] * C2);
                float e3 = exp2f(sv[3] * C2);
                *(uint2*)&psw[mi * 16 + l16][ns * 16 + quad * 4] =
                    (uint2){pk2(e0, e1), pk2(e2, e3)};
            }
        }

        // ---- O += P V (V(kt) already resident; psw same-wave) ----
        const char* vsb = (const char*)&vsm[s][0];
        #pragma unroll
        for (int kc = 0; kc < 2; ++kc) {
            bf16x8 pf[2];
            #pragma unroll
            for (int mi = 0; mi < 2; ++mi) {
                const uint16_t* pp = &psw[mi * 16 + l16][kc * 32 + quad * 8];
                ((uint2*)&pf[mi])[0] = *(const uint2*)(pp);
                ((uint2*)&pf[mi])[1] = *(const uint2*)(pp + 4);
            }
            #pragma unroll
            for (int ds = 0; ds < 5; ++ds) {
                const int vr = ds * 16 + l16;
                bf16x8 vf = *(const bf16x8*)(vsb + vr * 128 +
                    ((kc * 64 + quad * 16) ^ ((vr & 7) << 4)));
                #pragma unroll
                for (int mi = 0; mi < 2; ++mi)
                    Oacc[mi][ds] = MFMA16(pf[mi], vf, Oacc[mi][ds]);
            }
            #pragma unroll
            for (int mi = 0; mi < 2; ++mi)
                Oacc[mi][5] = MFMA16(pf[mi], vf5, Oacc[mi][5]);
        }
    }

    // epilogue: l = ones-column (col 0 of slab 5); O/l -> split hi/lo bf16 ab
    #pragma unroll
    for (int mi = 0; mi < 2; ++mi)
        #pragma unroll
        for (int r = 0; r < 4; ++r) {
            float l = __shfl(Oacc[mi][5][r], lane & 48);
            float inv = 1.f / l;
            const int srow = q0 + w * 32 + mi * 16 + quad * 4 + r;
            const size_t rowbase = (size_t)srow * HID + h * HD;
            #pragma unroll
            for (int ds = 0; ds < 5; ++ds) {
                float f = Oacc[mi][ds][r] * inv;
                uint16_t hi = f2bf(f);
                abh[rowbase + ds * 16 + l16] = hi;
                abl[rowbase + ds * 16 + l16] = f2bf(f - bf2f(hi));
            }
        }
}

extern "C" void kernel_launch(void* const* d_in, const int* in_sizes, int n_in,
                              void* d_out, int out_size, void* d_ws, size_t ws_size,
                              hipStream_t stream)
{
    const float* x     = (const float*)d_in[0];
    const float* cosb  = (const float*)d_in[1];
    const float* sinb  = (const float*)d_in[2];
    const float* Wqkv  = (const float*)d_in[3];
    const float* bqkv  = (const float*)d_in[4];
    const float* Wproj = (const float*)d_in[5];
    const float* bproj = (const float*)d_in[6];
    float* out = (float*)d_out;

    const size_t E = (size_t)NH * S_LEN * HD;   // 10,485,760 (= S*HID)
    uint16_t* qb  = (uint16_t*)d_ws;            // [h][s][80]
    uint16_t* kb  = qb + E;                     // [h][s][80]
    uint16_t* vt  = kb + E;                     // [h][80][s]
    uint16_t* xh  = vt + E;                     // x_hi [s][1280]; later ab_hi
    uint16_t* xl  = xh + E;                     // x_lo;           later ab_lo
    uint16_t* wth = xl + E;                     // W^T hi
    uint16_t* wtl = wth + (size_t)3 * HID * HID;

    xsplit_kernel<<<(S_LEN * HID) / (256 * 4), 256, 0, stream>>>(x, xh, xl);
    wsplit_kernel<3 * HID><<<dim3(3 * HID / 32, HID / 32), 256, 0, stream>>>(Wqkv, wth, wtl);
    // QKV: BM=256, BN=256, waves 2x4, schedule B, W1=4  (known-good)
    gemm8p<256, 3 * HID, 256, 2, 4, 1, 4>
        <<<dim3(3 * HID / 256, S_LEN / 256), 512, 0, stream>>>(
        xh, xl, wth, wtl, bqkv, nullptr, qb, kb, vt);
    rope_kernel<<<(S_LEN * NH * 40) / 256, 256, 0, stream>>>(qb, kb, cosb, sinb);
    attn_kernel<<<dim3(LCH / BQ, NH, NCH), 512, 0, stream>>>(qb, kb, vt, xh, xl);
    wsplit_kernel<HID><<<dim3(HID / 32, HID / 32), 256, 0, stream>>>(Wproj, wth, wtl);
    // proj: BM=256, BN=160 -> 256 blocks, waves 4x2, schedule B, W1=3 (R4 config)
    gemm8p<256, HID, 160, 4, 2, 0, 3>
        <<<dim3(HID / 160, S_LEN / 256), 512, 0, stream>>>(
        xh, xl, wth, wtl, bproj, out, nullptr, nullptr, nullptr);
}

// Round 9
// 477.919 us; speedup vs baseline: 1.1829x; 1.0320x over previous
//
#include <hip/hip_runtime.h>
#include <math.h>
#include <stdint.h>

#define S_LEN 8192
#define HID   1280
#define NH    16
#define HD    80
#define LCH   1024
#define NCH   8

typedef __attribute__((ext_vector_type(8))) short bf16x8;
typedef __attribute__((ext_vector_type(4))) float f32x4;

__device__ __forceinline__ uint16_t f2bf(float f) {
    union { float f; uint32_t u; } v; v.f = f;
    uint32_t r = v.u + 0x7FFF + ((v.u >> 16) & 1);   // RNE
    return (uint16_t)(r >> 16);
}
__device__ __forceinline__ float bf2f(uint16_t h) {
    union { uint32_t u; float f; } v; v.u = ((uint32_t)h) << 16;
    return v.f;
}
__device__ __forceinline__ uint16_t f2bf_trunc(float f) {
    union { float f; uint32_t u; } v; v.f = f;
    return (uint16_t)(v.u >> 16);
}
__device__ __forceinline__ uint32_t pk2(float a, float b) {   // trunc-bf16 pair pack
    union { float f; uint32_t u; } x, y; x.f = a; y.f = b;
    return (x.u >> 16) | (y.u & 0xFFFF0000u);
}

__device__ __forceinline__ void glds16(const void* g, void* l) {
    __builtin_amdgcn_global_load_lds(
        (const __attribute__((address_space(1))) uint32_t*)g,
        (__attribute__((address_space(3))) uint32_t*)l,
        16, 0, 0);
}

#define MFMA16(a, b, c) __builtin_amdgcn_mfma_f32_16x16x32_bf16(a, b, c, 0, 0, 0)
#define SB()  __builtin_amdgcn_sched_barrier(0)
#define BAR() __builtin_amdgcn_s_barrier()

template<int N> __device__ __forceinline__ void vmwait() {
    if constexpr (N == 0) asm volatile("s_waitcnt vmcnt(0)" ::: "memory");
    else if constexpr (N == 2) asm volatile("s_waitcnt vmcnt(2)" ::: "memory");
    else if constexpr (N == 3) asm volatile("s_waitcnt vmcnt(3)" ::: "memory");
    else if constexpr (N == 4) asm volatile("s_waitcnt vmcnt(4)" ::: "memory");
}

// stage one [rows x 32] bf16 K-tile (nbytes = rows*64) into LDS, linear dest,
// global source pre-swizzled per lane so the ds_read-side XOR swizzle matches.
// chunk advance: 1024 B LDS <-> 16 rows * 2560 B global = off*40.
__device__ __forceinline__ void stage_tile(const char* gsrc, char* dst, int w,
                                           int kt, int nbytes)
{
    const char* sp = gsrc + (size_t)kt * 64;
    int off = w * 1024;
    glds16(sp + (size_t)off * 40, dst + off);
    off += 8192;
    if (off < nbytes) glds16(sp + (size_t)off * 40, dst + off);
}

// ---------------- prepass: split x fp32 -> hi/lo bf16 (same layout) ----------------
__global__ __launch_bounds__(256)
void xsplit_kernel(const float* __restrict__ x, uint16_t* __restrict__ xh,
                   uint16_t* __restrict__ xl)
{
    int idx = (blockIdx.x * 256 + threadIdx.x) * 4;
    float4 v = *(const float4*)(x + idx);
    ushort4 hi, lo;
    hi.x = f2bf(v.x); lo.x = f2bf(v.x - bf2f(hi.x));
    hi.y = f2bf(v.y); lo.y = f2bf(v.y - bf2f(hi.y));
    hi.z = f2bf(v.z); lo.z = f2bf(v.z - bf2f(hi.z));
    hi.w = f2bf(v.w); lo.w = f2bf(v.w - bf2f(hi.w));
    *(ushort4*)(xh + idx) = hi;
    *(ushort4*)(xl + idx) = lo;
}

// ---------------- prepass: W [1280][ND] fp32 -> W^T [ND][1280] hi/lo bf16 ----------------
template<int ND>
__global__ __launch_bounds__(256)
void wsplit_kernel(const float* __restrict__ W, uint16_t* __restrict__ Wth,
                   uint16_t* __restrict__ Wtl)
{
    __shared__ float t[32][33];
    const int tid = threadIdx.x;
    const int n0 = blockIdx.x * 32;
    const int k0 = blockIdx.y * 32;
    for (int i = tid; i < 1024; i += 256) {
        int r = i >> 5, c = i & 31;
        t[r][c] = W[(size_t)(k0 + r) * ND + n0 + c];
    }
    __syncthreads();
    for (int i = tid; i < 1024; i += 256) {
        int r = i >> 5, c = i & 31;          // r: n offset, c: k offset
        float f = t[c][r];
        uint16_t hi = f2bf(f);
        size_t o = (size_t)(n0 + r) * HID + k0 + c;
        Wth[o] = hi;
        Wtl[o] = f2bf(f - bf2f(hi));
    }
}

// ---------------- split-bf16 MFMA GEMM, 2-phase counted-vmcnt pipeline ----------------
// P1 {read ah,bh(s) | stage Ah,Bh(t) | vmcnt(W1) | bar | MFMA hh}
// P2 {read bl,al(s) | stage Bl,Al(t) | vmcnt(W1) | bar | MFMA hl; MFMA lh}
// FIFO audit (per wave): at P1's wait, outstanding = BlAl(s)[older] + AhBh(t)
// -> vmcnt(W1) drains BlAl(s) before P2 reads it. At P2's wait, outstanding =
// AhBh(t)[older] + BlAl(t) -> drains AhBh(t) before P1(kt+1) reads it. Every
// buffer lands one full phase before its first ds_read; vmcnt never 0 in loop.
// Accumulation order per K-tile (hh, hl, lh) identical to the 3-phase version.
// QKV: 4 loads/group all waves -> W1=4. proj: groups 3-4 -> W1=3.
template<int BM, int ND, int BN, int NWM, int NWN, int EPI, int W1>
__global__ __launch_bounds__(512, 2)
void gemm8p(const uint16_t* __restrict__ Ahp, const uint16_t* __restrict__ Alp,
            const uint16_t* __restrict__ Bth, const uint16_t* __restrict__ Btl,
            const float* __restrict__ bias, float* __restrict__ oF,
            uint16_t* __restrict__ oq, uint16_t* __restrict__ ok,
            uint16_t* __restrict__ ov)
{
    constexpr int MI  = BM / (NWM * 16);
    constexpr int NI  = BN / (NWN * 16);
    constexpr int ABYTES = BM * 64;
    constexpr int BBYTES = BN * 64;
    constexpr int NT = HID / 32;             // 40 K-tiles
    static_assert(NWM * NWN == 8, "8 waves");
    static_assert(BM % (NWM * 16) == 0 && BN % (NWN * 16) == 0, "tile split");

    __shared__ __align__(1024) uint16_t AsH[2][ABYTES / 2];
    __shared__ __align__(1024) uint16_t AsL[2][ABYTES / 2];
    __shared__ __align__(1024) uint16_t BsH[2][BBYTES / 2];
    __shared__ __align__(1024) uint16_t BsL[2][BBYTES / 2];

    const int tid  = threadIdx.x;
    const int w    = tid >> 6;
    const int lane = tid & 63;
    const int quad = lane >> 4;
    const int l16  = lane & 15;
    const int wm   = w / NWN;
    const int wn   = w % NWN;

    const int n0 = blockIdx.x * BN;
    const int m0 = blockIdx.y * BM;

    const size_t stg = (size_t)(lane >> 2) * (HID * 2)
                     + (size_t)(((lane & 3) ^ ((lane >> 3) & 3)) << 4);
    const char* gAh = (const char*)Ahp + (size_t)m0 * (HID * 2) + stg;
    const char* gAl = (const char*)Alp + (size_t)m0 * (HID * 2) + stg;
    const char* gBh = (const char*)Bth + (size_t)n0 * (HID * 2) + stg;
    const char* gBl = (const char*)Btl + (size_t)n0 * (HID * 2) + stg;

    const int swz  = (quad ^ ((l16 >> 1) & 3)) << 4;
    const int aoff = (wm * (MI * 16) + l16) * 64 + swz;
    const int boff = (wn * (NI * 16) + l16) * 64 + swz;

    f32x4 acc[MI][NI];
    #pragma unroll
    for (int mi = 0; mi < MI; ++mi)
        #pragma unroll
        for (int ni = 0; ni < NI; ++ni) acc[mi][ni] = (f32x4){0.f, 0.f, 0.f, 0.f};

    // prologue: stage kt=0 in group order [AhBh], [BlAl]
    stage_tile(gAh, (char*)AsH[0], w, 0, ABYTES);
    stage_tile(gBh, (char*)BsH[0], w, 0, BBYTES);
    stage_tile(gBl, (char*)BsL[0], w, 0, BBYTES);
    stage_tile(gAl, (char*)AsL[0], w, 0, ABYTES);
    SB(); vmwait<W1>(); BAR(); SB();         // AhBh(0) landed; BlAl(0) in flight

    for (int kt = 0; kt < NT - 1; ++kt) {
        const int s = kt & 1, t = s ^ 1;

        // ---- P1: hh ----
        bf16x8 ah[MI], bh[NI];
        #pragma unroll
        for (int mi = 0; mi < MI; ++mi)
            ah[mi] = *(const bf16x8*)((const char*)AsH[s] + aoff + mi * 1024);
        #pragma unroll
        for (int ni = 0; ni < NI; ++ni)
            bh[ni] = *(const bf16x8*)((const char*)BsH[s] + boff + ni * 1024);
        stage_tile(gAh, (char*)AsH[t], w, kt + 1, ABYTES);
        stage_tile(gBh, (char*)BsH[t], w, kt + 1, BBYTES);
        SB(); vmwait<W1>(); BAR(); SB();     // drains BlAl(s)
        __builtin_amdgcn_s_setprio(1);
        #pragma unroll
        for (int mi = 0; mi < MI; ++mi)
            #pragma unroll
            for (int ni = 0; ni < NI; ++ni)
                acc[mi][ni] = MFMA16(ah[mi], bh[ni], acc[mi][ni]);
        __builtin_amdgcn_s_setprio(0);

        // ---- P2: hl + lh ----
        bf16x8 bl[NI], al[MI];
        #pragma unroll
        for (int ni = 0; ni < NI; ++ni)
            bl[ni] = *(const bf16x8*)((const char*)BsL[s] + boff + ni * 1024);
        #pragma unroll
        for (int mi = 0; mi < MI; ++mi)
            al[mi] = *(const bf16x8*)((const char*)AsL[s] + aoff + mi * 1024);
        stage_tile(gBl, (char*)BsL[t], w, kt + 1, BBYTES);
        stage_tile(gAl, (char*)AsL[t], w, kt + 1, ABYTES);
        SB(); vmwait<W1>(); BAR(); SB();     // drains AhBh(t)
        __builtin_amdgcn_s_setprio(1);
        #pragma unroll
        for (int mi = 0; mi < MI; ++mi)
            #pragma unroll
            for (int ni = 0; ni < NI; ++ni)
                acc[mi][ni] = MFMA16(ah[mi], bl[ni], acc[mi][ni]);
        #pragma unroll
        for (int mi = 0; mi < MI; ++mi)
            #pragma unroll
            for (int ni = 0; ni < NI; ++ni)
                acc[mi][ni] = MFMA16(al[mi], bh[ni], acc[mi][ni]);
        __builtin_amdgcn_s_setprio(0);
    }

    // ---- peeled last K-tile (no staging) ----
    {
        const int s = (NT - 1) & 1;
        bf16x8 ah[MI], bh[NI];
        #pragma unroll
        for (int mi = 0; mi < MI; ++mi)
            ah[mi] = *(const bf16x8*)((const char*)AsH[s] + aoff + mi * 1024);
        #pragma unroll
        for (int ni = 0; ni < NI; ++ni)
            bh[ni] = *(const bf16x8*)((const char*)BsH[s] + boff + ni * 1024);
        SB(); vmwait<0>(); BAR(); SB();      // all of BlAl(s) landed, all waves
        __builtin_amdgcn_s_setprio(1);
        #pragma unroll
        for (int mi = 0; mi < MI; ++mi)
            #pragma unroll
            for (int ni = 0; ni < NI; ++ni)
                acc[mi][ni] = MFMA16(ah[mi], bh[ni], acc[mi][ni]);
        __builtin_amdgcn_s_setprio(0);

        bf16x8 bl[NI], al[MI];
        #pragma unroll
        for (int ni = 0; ni < NI; ++ni)
            bl[ni] = *(const bf16x8*)((const char*)BsL[s] + boff + ni * 1024);
        #pragma unroll
        for (int mi = 0; mi < MI; ++mi)
            al[mi] = *(const bf16x8*)((const char*)AsL[s] + aoff + mi * 1024);
        #pragma unroll
        for (int mi = 0; mi < MI; ++mi)
            #pragma unroll
            for (int ni = 0; ni < NI; ++ni)
                acc[mi][ni] = MFMA16(ah[mi], bl[ni], acc[mi][ni]);
        #pragma unroll
        for (int mi = 0; mi < MI; ++mi)
            #pragma unroll
            for (int ni = 0; ni < NI; ++ni)
                acc[mi][ni] = MFMA16(al[mi], bh[ni], acc[mi][ni]);
    }

    // ---- epilogue ----
    #pragma unroll
    for (int ni = 0; ni < NI; ++ni) {
        const int n = n0 + wn * (NI * 16) + ni * 16 + l16;
        const float bv = bias[n];
        if constexpr (EPI) {
            const int tq  = n / HID;
            const int rem = n - tq * HID;
            const int h   = rem / HD;
            const int d   = rem - h * HD;
            #pragma unroll
            for (int mi = 0; mi < MI; ++mi) {
                const int mb = m0 + wm * (MI * 16) + mi * 16 + quad * 4;
                if (tq == 2) {
                    ushort4 pv;
                    pv.x = f2bf(acc[mi][ni][0] + bv);
                    pv.y = f2bf(acc[mi][ni][1] + bv);
                    pv.z = f2bf(acc[mi][ni][2] + bv);
                    pv.w = f2bf(acc[mi][ni][3] + bv);
                    *(ushort4*)&ov[((size_t)h * HD + d) * S_LEN + mb] = pv;
                } else {
                    uint16_t* dst = (tq == 0) ? oq : ok;
                    #pragma unroll
                    for (int r = 0; r < 4; ++r)
                        dst[((size_t)h * S_LEN + (mb + r)) * HD + d] =
                            f2bf(acc[mi][ni][r] + bv);
                }
            }
        } else {
            #pragma unroll
            for (int mi = 0; mi < MI; ++mi) {
                const int mb = m0 + wm * (MI * 16) + mi * 16 + quad * 4;
                #pragma unroll
                for (int r = 0; r < 4; ++r)
                    oF[(size_t)(mb + r) * ND + n] = acc[mi][ni][r] + bv;
            }
        }
    }
}

// ---------------- rope: in-place on bf16 q and k, layout [h][s][80] (R4 scalar) --------
__global__ __launch_bounds__(256)
void rope_kernel(uint16_t* __restrict__ qb, uint16_t* __restrict__ kb,
                 const float* __restrict__ cosb, const float* __restrict__ sinb)
{
    int idx = blockIdx.x * 256 + threadIdx.x;
    int d = idx % 40;
    int t = idx / 40;
    int s = t % S_LEN;
    int h = t / S_LEN;
    size_t base = ((size_t)h * S_LEN + s) * HD;
    float c1 = cosb[s * HD + d],      s1 = sinb[s * HD + d];
    float c2 = cosb[s * HD + d + 40], s2 = sinb[s * HD + d + 40];
    float q1 = bf2f(qb[base + d]), q2 = bf2f(qb[base + d + 40]);
    qb[base + d]      = f2bf(q1 * c1 - q2 * s1);
    qb[base + d + 40] = f2bf(q2 * c2 + q1 * s2);
    float k1 = bf2f(kb[base + d]), k2 = bf2f(kb[base + d + 40]);
    kb[base + d]      = f2bf(k1 * c1 - k2 * s1);
    kb[base + d + 40] = f2bf(k2 * c2 + k1 * s2);
}

// ---------------- MFMA flash attention, BQ=256, 8 waves, conflict-free LDS ------------
// (R4 verbatim: 2 barriers/K-tile, K dbuf, V single-buffered)
#define BQ 256
#define BK 64

__device__ __forceinline__ void kstage(const char* kg, char* dst, int w, int lane)
{
    int p = w * 1024 + lane * 16;
    {   // regA: phys (row, sl) holds global d-slot sl^(row&7)
        int row = p >> 7;
        int sl  = (p >> 4) & 7;
        glds16(kg + row * 160 + ((sl ^ (row & 7)) << 4), dst + p);
    }
    int p2 = p + 8192;
    if (p2 < 10240) {   // regB: waves 0,1; identity mapping, d-slots 8,9
        int q   = p2 - 8192;
        int row = q >> 5;
        int sl  = (q >> 4) & 1;
        glds16(kg + row * 160 + 128 + (sl << 4), dst + p2);
    }
}

__global__ __launch_bounds__(512, 4)
void attn_kernel(const uint16_t* __restrict__ qb, const uint16_t* __restrict__ kb,
                 const uint16_t* __restrict__ vt,
                 uint16_t* __restrict__ abh, uint16_t* __restrict__ abl)
{
    __shared__ __align__(16) uint16_t smemA[BQ * HD];     // 40960 B: Q staging, then psw
    __shared__ __align__(16) uint16_t ksm[2][BK * HD];    // K tiles dbuf (regA+regB)
    __shared__ __align__(16) uint16_t vsm[HD * BK];       // V tile [d][k], swizzled

    const int tid  = threadIdx.x;
    const int w    = tid >> 6;
    const int lane = tid & 63;
    const int quad = lane >> 4;
    const int l16  = lane & 15;

    const int qt = blockIdx.x;
    const int h  = blockIdx.y;
    const int c  = blockIdx.z;
    const int q0 = c * LCH + qt * BQ;

    uint16_t (*psw)[68] = (uint16_t(*)[68])smemA + w * 32;

    {
        const char* qg = (const char*)(qb + ((size_t)h * S_LEN + q0) * HD);
        for (int off = w * 1024; off < BQ * HD * 2; off += 8192)
            glds16(qg + off + lane * 16, (char*)smemA + off);
    }
    __syncthreads();   // Q staged

    bf16x8 qfr[2][3];
    #pragma unroll
    for (int mi = 0; mi < 2; ++mi) {
        const int row = w * 32 + mi * 16 + l16;
        qfr[mi][0] = *(const bf16x8*)&smemA[row * HD + quad * 8];
        qfr[mi][1] = *(const bf16x8*)&smemA[row * HD + 32 + quad * 8];
        bf16x8 z = {0, 0, 0, 0, 0, 0, 0, 0};
        qfr[mi][2] = (quad < 2) ? *(const bf16x8*)&smemA[row * HD + 64 + quad * 8] : z;
    }

    bf16x8 vf5;
    {
        short o = (l16 == 0) ? (short)0x3F80 : (short)0;
        vf5 = (bf16x8){o, o, o, o, o, o, o, o};
    }

    f32x4 Oacc[2][6];
    #pragma unroll
    for (int mi = 0; mi < 2; ++mi)
        #pragma unroll
        for (int d = 0; d < 6; d++) Oacc[mi][d] = (f32x4){0.f, 0.f, 0.f, 0.f};

    const float C2 = 0.11180339887498949f * 1.4426950408889634f;  // 1/sqrt(80)*log2e
    const char* kg0 = (const char*)(kb + ((size_t)h * S_LEN + c * LCH) * HD);
    const size_t vrow_stride = (size_t)S_LEN * 2;
    const char* vg0 = (const char*)vt + (size_t)h * HD * S_LEN * 2 + (size_t)(c * LCH) * 2;

    kstage(kg0, (char*)&ksm[0][0], w, lane);

    for (int kt = 0; kt < LCH / BK; ++kt) {
        __syncthreads();   // barrier A: K(kt) staged (drain covered by PV(kt-1))

        // issue V(kt): phys (row, col) <- global col' = col ^ ((row&7)<<4)
        {
            const char* vg = vg0 + (size_t)(kt * BK) * 2;
            for (int off = w * 1024; off < HD * BK * 2; off += 8192) {
                int o   = off + lane * 16;
                int row = o >> 7;
                int col = o & 127;
                glds16(vg + (size_t)row * vrow_stride + (col ^ ((row & 7) << 4)),
                       (char*)vsm + off);
            }
        }

        // ---- S^T = K Q^T (swapped): rows=k, cols=q; softmax+pack per ns ----
        const char* ksb = (const char*)&ksm[kt & 1][0];
        #pragma unroll
        for (int ns = 0; ns < 4; ++ns) {
            const int kr = ns * 16 + l16;
            const int sw = (kr & 7) << 4;
            bf16x8 kf0 = *(const bf16x8*)(ksb + kr * 128 + ((quad * 16) ^ sw));
            bf16x8 kf1 = *(const bf16x8*)(ksb + kr * 128 + ((64 + quad * 16) ^ sw));
            bf16x8 z = {0, 0, 0, 0, 0, 0, 0, 0};
            bf16x8 kf2 = (quad < 2)
                ? *(const bf16x8*)(ksb + 8192 + kr * 32 + quad * 16) : z;
            #pragma unroll
            for (int mi = 0; mi < 2; ++mi) {
                f32x4 s = (f32x4){0.f, 0.f, 0.f, 0.f};
                s = MFMA16(kf0, qfr[mi][0], s);
                s = MFMA16(kf1, qfr[mi][1], s);
                s = MFMA16(kf2, qfr[mi][2], s);
                float e0 = exp2f(s[0] * C2);
                float e1 = exp2f(s[1] * C2);
                float e2 = exp2f(s[2] * C2);
                float e3 = exp2f(s[3] * C2);
                *(uint2*)&psw[mi * 16 + l16][ns * 16 + quad * 4] =
                    (uint2){pk2(e0, e1), pk2(e2, e3)};
            }
        }

        __syncthreads();   // barrier B: V(kt) staged (drain covered by QK)

        if (kt + 1 < LCH / BK)
            kstage(kg0 + (size_t)(kt + 1) * BK * HD * 2,
                   (char*)&ksm[(kt + 1) & 1][0], w, lane);

        // ---- O += P V ----
        #pragma unroll
        for (int kc = 0; kc < 2; ++kc) {
            bf16x8 pf[2];
            #pragma unroll
            for (int mi = 0; mi < 2; ++mi) {
                const uint16_t* pp = &psw[mi * 16 + l16][kc * 32 + quad * 8];
                ((uint2*)&pf[mi])[0] = *(const uint2*)(pp);
                ((uint2*)&pf[mi])[1] = *(const uint2*)(pp + 4);
            }
            #pragma unroll
            for (int ds = 0; ds < 5; ++ds) {
                const int vr = ds * 16 + l16;
                bf16x8 vf = *(const bf16x8*)((const char*)vsm + vr * 128 +
                    ((kc * 64 + quad * 16) ^ ((vr & 7) << 4)));
                #pragma unroll
                for (int mi = 0; mi < 2; ++mi)
                    Oacc[mi][ds] = MFMA16(pf[mi], vf, Oacc[mi][ds]);
            }
            #pragma unroll
            for (int mi = 0; mi < 2; ++mi)
                Oacc[mi][5] = MFMA16(pf[mi], vf5, Oacc[mi][5]);
        }
    }

    // epilogue: l = ones-column (col 0 of slab 5); O/l -> split hi/lo bf16 ab
    #pragma unroll
    for (int mi = 0; mi < 2; ++mi)
        #pragma unroll
        for (int r = 0; r < 4; ++r) {
            float l = __shfl(Oacc[mi][5][r], lane & 48);
            float inv = 1.f / l;
            const int srow = q0 + w * 32 + mi * 16 + quad * 4 + r;
            const size_t rowbase = (size_t)srow * HID + h * HD;
            #pragma unroll
            for (int ds = 0; ds < 5; ++ds) {
                float f = Oacc[mi][ds][r] * inv;
                uint16_t hi = f2bf(f);
                abh[rowbase + ds * 16 + l16] = hi;
                abl[rowbase + ds * 16 + l16] = f2bf(f - bf2f(hi));
            }
        }
}

extern "C" void kernel_launch(void* const* d_in, const int* in_sizes, int n_in,
                              void* d_out, int out_size, void* d_ws, size_t ws_size,
                              hipStream_t stream)
{
    const float* x     = (const float*)d_in[0];
    const float* cosb  = (const float*)d_in[1];
    const float* sinb  = (const float*)d_in[2];
    const float* Wqkv  = (const float*)d_in[3];
    const float* bqkv  = (const float*)d_in[4];
    const float* Wproj = (const float*)d_in[5];
    const float* bproj = (const float*)d_in[6];
    float* out = (float*)d_out;

    const size_t E = (size_t)NH * S_LEN * HD;   // 10,485,760 (= S*HID)
    uint16_t* qb  = (uint16_t*)d_ws;            // [h][s][80]
    uint16_t* kb  = qb + E;                     // [h][s][80]
    uint16_t* vt  = kb + E;                     // [h][80][s]
    uint16_t* xh  = vt + E;                     // x_hi [s][1280]; later ab_hi
    uint16_t* xl  = xh + E;                     // x_lo;           later ab_lo
    uint16_t* wth = xl + E;                     // W^T hi
    uint16_t* wtl = wth + (size_t)3 * HID * HID;

    xsplit_kernel<<<(S_LEN * HID) / (256 * 4), 256, 0, stream>>>(x, xh, xl);
    wsplit_kernel<3 * HID><<<dim3(3 * HID / 32, HID / 32), 256, 0, stream>>>(Wqkv, wth, wtl);
    // QKV: BM=256, BN=256, waves 2x4, 2-phase, W1=4
    gemm8p<256, 3 * HID, 256, 2, 4, 1, 4>
        <<<dim3(3 * HID / 256, S_LEN / 256), 512, 0, stream>>>(
        xh, xl, wth, wtl, bqkv, nullptr, qb, kb, vt);
    rope_kernel<<<(S_LEN * NH * 40) / 256, 256, 0, stream>>>(qb, kb, cosb, sinb);
    attn_kernel<<<dim3(LCH / BQ, NH, NCH), 512, 0, stream>>>(qb, kb, vt, xh, xl);
    wsplit_kernel<HID><<<dim3(HID / 32, HID / 32), 256, 0, stream>>>(Wproj, wth, wtl);
    // proj: BM=256, BN=160 -> 256 blocks, waves 4x2, 2-phase, W1=3
    gemm8p<256, HID, 160, 4, 2, 0, 3>
        <<<dim3(HID / 160, S_LEN / 256), 512, 0, stream>>>(
        xh, xl, wth, wtl, bproj, out, nullptr, nullptr, nullptr);
}